// Round 1
// baseline (6196.968 us; speedup 1.0000x reference)
//
#include <hip/hip_runtime.h>
#include <math.h>

#define NN 100000
#define NE 640000
#define H 128
#define AD 25
#define ED 10
#define RD 64
#define NL 4

__device__ __forceinline__ float gelu_t(float x) {
    // tanh-approx GELU, matches jax.nn.gelu(approximate=True)
    float t = tanhf(0.7978845608028654f * (x + 0.044715f * x * x * x));
    return 0.5f * x * (1.0f + t);
}
__device__ __forceinline__ float sigm(float x) {
    return 1.0f / (1.0f + expf(-x));
}

// degree count (clipped to >=1 at use site)
__global__ void k_count(const int* __restrict__ ei, float* __restrict__ cnt) {
    int e = blockIdx.x * 256 + threadIdx.x;
    if (e < NE) atomicAdd(&cnt[ei[NE + e]], 1.0f);
}

// O[n,:] = gelu(A[n,:]@W1 + b1) @ W2 + b2      A:[nrows,K1], W1:[K1,128], W2:[128,128]
// 64-row tile per block, 256 thr, thread owns 8 rows x 4 cols.
template <int K1>
__global__ void __launch_bounds__(256, 4)
k_mlp2(const float* __restrict__ A, float* __restrict__ O,
       const float* __restrict__ W1, const float* __restrict__ B1,
       const float* __restrict__ W2, const float* __restrict__ B2, int nrows) {
    constexpr int SA = K1 + 1;
    __shared__ float st[64 * 129];
    const int row0 = blockIdx.x * 64;
    const int tid = threadIdx.x;
    const int tx = tid & 31, ty = tid >> 5, r0 = ty * 8;

    for (int idx = tid; idx < 64 * K1; idx += 256) {
        int r = idx / K1, k = idx - r * K1;
        int row = row0 + r;
        st[r * SA + k] = (row < nrows) ? A[row * K1 + k] : 0.0f;
    }
    __syncthreads();

    float acc[8][4];
#pragma unroll
    for (int i = 0; i < 8; ++i) { acc[i][0] = acc[i][1] = acc[i][2] = acc[i][3] = 0.0f; }
    for (int k = 0; k < K1; ++k) {
        const float4 w = *(const float4*)(W1 + k * H + 4 * tx);
#pragma unroll
        for (int i = 0; i < 8; ++i) {
            float a = st[(r0 + i) * SA + k];
            acc[i][0] = fmaf(a, w.x, acc[i][0]);
            acc[i][1] = fmaf(a, w.y, acc[i][1]);
            acc[i][2] = fmaf(a, w.z, acc[i][2]);
            acc[i][3] = fmaf(a, w.w, acc[i][3]);
        }
    }
    __syncthreads();  // all GEMM1 reads done before hid overwrite
    const float4 b1 = *(const float4*)(B1 + 4 * tx);
#pragma unroll
    for (int i = 0; i < 8; ++i) {
        float* p = st + (r0 + i) * 129 + 4 * tx;
        p[0] = gelu_t(acc[i][0] + b1.x);
        p[1] = gelu_t(acc[i][1] + b1.y);
        p[2] = gelu_t(acc[i][2] + b1.z);
        p[3] = gelu_t(acc[i][3] + b1.w);
    }
    __syncthreads();
#pragma unroll
    for (int i = 0; i < 8; ++i) { acc[i][0] = acc[i][1] = acc[i][2] = acc[i][3] = 0.0f; }
    for (int k = 0; k < H; ++k) {
        const float4 w = *(const float4*)(W2 + k * H + 4 * tx);
#pragma unroll
        for (int i = 0; i < 8; ++i) {
            float a = st[(r0 + i) * 129 + k];
            acc[i][0] = fmaf(a, w.x, acc[i][0]);
            acc[i][1] = fmaf(a, w.y, acc[i][1]);
            acc[i][2] = fmaf(a, w.z, acc[i][2]);
            acc[i][3] = fmaf(a, w.w, acc[i][3]);
        }
    }
    const float4 b2 = *(const float4*)(B2 + 4 * tx);
#pragma unroll
    for (int i = 0; i < 8; ++i) {
        int row = row0 + r0 + i;
        if (row < nrows) {
            float4 o;
            o.x = acc[i][0] + b2.x;
            o.y = acc[i][1] + b2.y;
            o.z = acc[i][2] + b2.z;
            o.w = acc[i][3] + b2.w;
            *(float4*)(O + row * H + 4 * tx) = o;
        }
    }
}

// Fused per-edge: ew = MLP2(edge_attr)  ->  msg = ew * m[src]  ->  atomicAdd agg[dst]
__global__ void __launch_bounds__(256, 4)
k_edge(const float* __restrict__ EA, const int* __restrict__ ei,
       const float* __restrict__ M, float* __restrict__ AGG,
       const float* __restrict__ W1, const float* __restrict__ B1,
       const float* __restrict__ W2, const float* __restrict__ B2) {
    __shared__ float sea[64 * ED];
    __shared__ float sh[64 * 129];
    const int e0 = blockIdx.x * 64;  // NE % 64 == 0
    const int tid = threadIdx.x;
    const int tx = tid & 31, ty = tid >> 5, r0 = ty * 8;

    for (int idx = tid; idx < 64 * ED; idx += 256)
        sea[idx] = EA[e0 * ED + idx];
    __syncthreads();

    float acc[8][4];
#pragma unroll
    for (int i = 0; i < 8; ++i) { acc[i][0] = acc[i][1] = acc[i][2] = acc[i][3] = 0.0f; }
    for (int k = 0; k < ED; ++k) {
        const float4 w = *(const float4*)(W1 + k * H + 4 * tx);
#pragma unroll
        for (int i = 0; i < 8; ++i) {
            float a = sea[(r0 + i) * ED + k];
            acc[i][0] = fmaf(a, w.x, acc[i][0]);
            acc[i][1] = fmaf(a, w.y, acc[i][1]);
            acc[i][2] = fmaf(a, w.z, acc[i][2]);
            acc[i][3] = fmaf(a, w.w, acc[i][3]);
        }
    }
    const float4 b1 = *(const float4*)(B1 + 4 * tx);
#pragma unroll
    for (int i = 0; i < 8; ++i) {
        float* p = sh + (r0 + i) * 129 + 4 * tx;
        p[0] = gelu_t(acc[i][0] + b1.x);
        p[1] = gelu_t(acc[i][1] + b1.y);
        p[2] = gelu_t(acc[i][2] + b1.z);
        p[3] = gelu_t(acc[i][3] + b1.w);
    }
    __syncthreads();
#pragma unroll
    for (int i = 0; i < 8; ++i) { acc[i][0] = acc[i][1] = acc[i][2] = acc[i][3] = 0.0f; }
    for (int k = 0; k < H; ++k) {
        const float4 w = *(const float4*)(W2 + k * H + 4 * tx);
#pragma unroll
        for (int i = 0; i < 8; ++i) {
            float a = sh[(r0 + i) * 129 + k];
            acc[i][0] = fmaf(a, w.x, acc[i][0]);
            acc[i][1] = fmaf(a, w.y, acc[i][1]);
            acc[i][2] = fmaf(a, w.z, acc[i][2]);
            acc[i][3] = fmaf(a, w.w, acc[i][3]);
        }
    }
    const float4 b2 = *(const float4*)(B2 + 4 * tx);
#pragma unroll
    for (int i = 0; i < 8; ++i) {
        int e = e0 + r0 + i;
        int s = ei[e], d = ei[NE + e];
        const float4 mv = *(const float4*)(M + s * H + 4 * tx);
        float vx = (acc[i][0] + b2.x) * mv.x;
        float vy = (acc[i][1] + b2.y) * mv.y;
        float vz = (acc[i][2] + b2.z) * mv.z;
        float vw = (acc[i][3] + b2.w) * mv.w;
        float* ap = AGG + d * H + 4 * tx;
        atomicAdd(ap + 0, vx);
        atomicAdd(ap + 1, vy);
        atomicAdd(ap + 2, vz);
        atomicAdd(ap + 3, vw);
    }
}

// gate = sigmoid([h, agg/cnt] @ GW + gb);  MOUT = h + gate * (agg/cnt)
__global__ void __launch_bounds__(256, 4)
k_gate(const float* __restrict__ HF, const float* __restrict__ AGG,
       const float* __restrict__ CNT,
       const float* __restrict__ GW, const float* __restrict__ GB,
       float* __restrict__ MOUT) {
    __shared__ float st[64 * 129];
    __shared__ float sinv[64];
    const int row0 = blockIdx.x * 64;
    const int tid = threadIdx.x;
    const int tx = tid & 31, ty = tid >> 5, r0 = ty * 8;

    if (tid < 64) {
        int row = row0 + tid;
        sinv[tid] = (row < NN) ? 1.0f / fmaxf(CNT[row], 1.0f) : 0.0f;
    }
    for (int idx = tid; idx < 64 * H; idx += 256) {
        int r = idx >> 7, k = idx & 127;
        int row = row0 + r;
        st[r * 129 + k] = (row < NN) ? HF[row * H + k] : 0.0f;
    }
    __syncthreads();

    float acc[8][4];
#pragma unroll
    for (int i = 0; i < 8; ++i) { acc[i][0] = acc[i][1] = acc[i][2] = acc[i][3] = 0.0f; }
    for (int k = 0; k < H; ++k) {
        const float4 w = *(const float4*)(GW + k * H + 4 * tx);
#pragma unroll
        for (int i = 0; i < 8; ++i) {
            float a = st[(r0 + i) * 129 + k];
            acc[i][0] = fmaf(a, w.x, acc[i][0]);
            acc[i][1] = fmaf(a, w.y, acc[i][1]);
            acc[i][2] = fmaf(a, w.z, acc[i][2]);
            acc[i][3] = fmaf(a, w.w, acc[i][3]);
        }
    }
    __syncthreads();
    for (int idx = tid; idx < 64 * H; idx += 256) {
        int r = idx >> 7, k = idx & 127;
        int row = row0 + r;
        st[r * 129 + k] = (row < NN) ? AGG[row * H + k] * sinv[r] : 0.0f;
    }
    __syncthreads();
    for (int k = 0; k < H; ++k) {
        const float4 w = *(const float4*)(GW + (H + k) * H + 4 * tx);
#pragma unroll
        for (int i = 0; i < 8; ++i) {
            float a = st[(r0 + i) * 129 + k];
            acc[i][0] = fmaf(a, w.x, acc[i][0]);
            acc[i][1] = fmaf(a, w.y, acc[i][1]);
            acc[i][2] = fmaf(a, w.z, acc[i][2]);
            acc[i][3] = fmaf(a, w.w, acc[i][3]);
        }
    }
    const float4 gb = *(const float4*)(GB + 4 * tx);
#pragma unroll
    for (int i = 0; i < 8; ++i) {
        int row = row0 + r0 + i;
        if (row < NN) {
            const float4 hv = *(const float4*)(HF + row * H + 4 * tx);
            const float* ap = st + (r0 + i) * 129 + 4 * tx;
            float4 o;
            o.x = fmaf(sigm(acc[i][0] + gb.x), ap[0], hv.x);
            o.y = fmaf(sigm(acc[i][1] + gb.y), ap[1], hv.y);
            o.z = fmaf(sigm(acc[i][2] + gb.z), ap[2], hv.z);
            o.w = fmaf(sigm(acc[i][3] + gb.w), ap[3], hv.w);
            *(float4*)(MOUT + row * H + 4 * tx) = o;
        }
    }
}

// LayerNorm over H per row: one wave per row
__global__ void k_ln(const float* __restrict__ A, float* __restrict__ O,
                     const float* __restrict__ G, const float* __restrict__ B) {
    int wid = blockIdx.x * 4 + (threadIdx.x >> 6);
    int lane = threadIdx.x & 63;
    if (wid >= NN) return;
    float2 v = *(const float2*)(A + wid * H + 2 * lane);
    float s = v.x + v.y;
#pragma unroll
    for (int o = 32; o > 0; o >>= 1) s += __shfl_xor(s, o);
    float mu = s * (1.0f / 128.0f);
    float dx = v.x - mu, dy = v.y - mu;
    float q = fmaf(dx, dx, dy * dy);
#pragma unroll
    for (int o = 32; o > 0; o >>= 1) q += __shfl_xor(q, o);
    float rs = rsqrtf(q * (1.0f / 128.0f) + 1e-5f);
    float2 g = *(const float2*)(G + 2 * lane);
    float2 b = *(const float2*)(B + 2 * lane);
    float2 ov;
    ov.x = fmaf(dx * rs, g.x, b.x);
    ov.y = fmaf(dy * rs, g.y, b.y);
    *(float2*)(O + wid * H + 2 * lane) = ov;
}

// three heads fused: out = gelu(h@w1+b1)@w2 + b2, one wave per node
__global__ void k_heads(const float* __restrict__ HF, float* __restrict__ OUT,
                        const float* __restrict__ w1a, const float* __restrict__ b1a,
                        const float* __restrict__ w2a, const float* __restrict__ b2a,
                        const float* __restrict__ w1b, const float* __restrict__ b1b,
                        const float* __restrict__ w2b, const float* __restrict__ b2b,
                        const float* __restrict__ w1c, const float* __restrict__ b1c,
                        const float* __restrict__ w2c, const float* __restrict__ b2c) {
    __shared__ float shh[4 * H];
    int node0 = blockIdx.x * 4;
    int tid = threadIdx.x;
    for (int idx = tid; idx < 4 * H; idx += 256) {
        int row = node0 + (idx >> 7);
        shh[idx] = (row < NN) ? HF[row * H + (idx & 127)] : 0.0f;
    }
    __syncthreads();
    int w = tid >> 6, lane = tid & 63;
    int node = node0 + w;
    if (node >= NN) return;
    const float* hr = shh + w * H;
    const float* w1s[3] = {w1a, w1b, w1c};
    const float* b1s[3] = {b1a, b1b, b1c};
    const float* w2s[3] = {w2a, w2b, w2c};
    const float* b2s[3] = {b2a, b2b, b2c};
#pragma unroll
    for (int t = 0; t < 3; ++t) {
        float a = b1s[t][lane];
        for (int k = 0; k < H; ++k) a = fmaf(hr[k], w1s[t][k * RD + lane], a);
        float p = gelu_t(a) * w2s[t][lane];
#pragma unroll
        for (int o = 32; o > 0; o >>= 1) p += __shfl_xor(p, o);
        if (lane == 0) OUT[t * NN + node] = p + b2s[t][0];
    }
}

extern "C" void kernel_launch(void* const* d_in, const int* in_sizes, int n_in,
                              void* d_out, int out_size, void* d_ws, size_t ws_size,
                              hipStream_t stream) {
    const float* x       = (const float*)d_in[0];
    const int*   ei      = (const int*)d_in[1];
    const float* ea      = (const float*)d_in[2];
    const float* enc_w1  = (const float*)d_in[3];
    const float* enc_b1  = (const float*)d_in[4];
    const float* enc_w2  = (const float*)d_in[5];
    const float* enc_b2  = (const float*)d_in[6];
    const float* edge_w1 = (const float*)d_in[7];
    const float* edge_b1 = (const float*)d_in[8];
    const float* edge_w2 = (const float*)d_in[9];
    const float* edge_b2 = (const float*)d_in[10];
    const float* msg_w1  = (const float*)d_in[11];
    const float* msg_b1  = (const float*)d_in[12];
    const float* msg_w2  = (const float*)d_in[13];
    const float* msg_b2  = (const float*)d_in[14];
    const float* gate_w  = (const float*)d_in[15];
    const float* gate_b  = (const float*)d_in[16];
    const float* ln_g    = (const float*)d_in[17];
    const float* ln_b    = (const float*)d_in[18];
    const float* hw[12];
    for (int t = 0; t < 12; ++t) hw[t] = (const float*)d_in[19 + t];

    float* ws  = (float*)d_ws;
    float* cnt = ws;                       // NN floats (padded to 100352)
    float* h   = ws + 100352;              // NN*H
    float* m   = h + (size_t)NN * H;       // NN*H
    float* agg = m + (size_t)NN * H;       // NN*H

    hipMemsetAsync(cnt, 0, NN * sizeof(float), stream);
    k_count<<<(NE + 255) / 256, 256, 0, stream>>>(ei, cnt);

    const int ntiles = (NN + 63) / 64;
    k_mlp2<AD><<<ntiles, 256, 0, stream>>>(x, h, enc_w1, enc_b1, enc_w2, enc_b2, NN);

    for (int l = 0; l < NL; ++l) {
        k_mlp2<H><<<ntiles, 256, 0, stream>>>(h, m,
            msg_w1 + (size_t)l * H * H, msg_b1 + l * H,
            msg_w2 + (size_t)l * H * H, msg_b2 + l * H, NN);
        hipMemsetAsync(agg, 0, (size_t)NN * H * sizeof(float), stream);
        k_edge<<<NE / 64, 256, 0, stream>>>(ea, ei, m, agg,
            edge_w1 + (size_t)l * ED * H, edge_b1 + l * H,
            edge_w2 + (size_t)l * H * H, edge_b2 + l * H);
        k_gate<<<ntiles, 256, 0, stream>>>(h, agg, cnt,
            gate_w + (size_t)l * 2 * H * H, gate_b + l * H, m);
        k_ln<<<(NN + 3) / 4, 256, 0, stream>>>(m, h, ln_g + l * H, ln_b + l * H);
    }

    k_heads<<<(NN + 3) / 4, 256, 0, stream>>>(h, (float*)d_out,
        hw[0], hw[1], hw[2], hw[3],
        hw[4], hw[5], hw[6], hw[7],
        hw[8], hw[9], hw[10], hw[11]);
}

// Round 2
// 4401.669 us; speedup vs baseline: 1.4079x; 1.4079x over previous
//
#include <hip/hip_runtime.h>
#include <math.h>

#define NN 100000
#define NE 640000
#define H 128
#define AD 25
#define ED 10
#define RD 64
#define NL 4
#define NB_E (NE / 64 + 1)        // 10001 edge blocks
#define NSB ((NN + 255) / 256)    // 391 scan blocks
#define CAP 256                   // max edges per block (63 + maxdeg)

__device__ __forceinline__ float gelu_t(float x) {
    float t = tanhf(0.7978845608028654f * (x + 0.044715f * x * x * x));
    return 0.5f * x * (1.0f + t);
}
__device__ __forceinline__ float sigm(float x) {
    return 1.0f / (1.0f + expf(-x));
}

// ---------------- sort infrastructure ----------------
__global__ void k_hist(const int* __restrict__ ei, int* __restrict__ hist) {
    int e = blockIdx.x * 256 + threadIdx.x;
    if (e < NE) atomicAdd(&hist[ei[NE + e]], 1);
}

__global__ void k_scan1(const int* __restrict__ hist, int* __restrict__ incl,
                        int* __restrict__ bsum) {
    __shared__ int s[256];
    int tid = threadIdx.x;
    int i = blockIdx.x * 256 + tid;
    s[tid] = (i < NN) ? hist[i] : 0;
    __syncthreads();
    for (int off = 1; off < 256; off <<= 1) {
        int t = (tid >= off) ? s[tid - off] : 0;
        __syncthreads();
        s[tid] += t;
        __syncthreads();
    }
    if (i < NN) incl[i] = s[tid];
    if (tid == 255) bsum[blockIdx.x] = s[255];
}

__global__ void k_scan2(int* __restrict__ bsum) {
    __shared__ int s[512];
    int tid = threadIdx.x;
    s[tid] = (tid < NSB) ? bsum[tid] : 0;
    __syncthreads();
    for (int off = 1; off < 512; off <<= 1) {
        int t = (tid >= off) ? s[tid - off] : 0;
        __syncthreads();
        s[tid] += t;
        __syncthreads();
    }
    if (tid < NSB) bsum[tid] = (tid > 0) ? s[tid - 1] : 0;  // exclusive
}

__global__ void k_scan3(const int* __restrict__ hist, const int* __restrict__ incl,
                        const int* __restrict__ bsum, int* __restrict__ row_ptr) {
    int i = blockIdx.x * 256 + threadIdx.x;
    if (i < NN) row_ptr[i] = bsum[blockIdx.x] + incl[i] - hist[i];  // exclusive
    if (i == 0) row_ptr[NN] = NE;
}

__global__ void k_scatter(const int* __restrict__ ei, int* __restrict__ cursor,
                          int* __restrict__ perm) {
    int e = blockIdx.x * 256 + threadIdx.x;
    if (e < NE) {
        int d = ei[NE + e];
        int pos = atomicAdd(&cursor[d], 1);
        perm[pos] = e;
    }
}

// node n -> block floor(row_ptr[n]/64); record per-block node range
__global__ void k_blockrange(const int* __restrict__ row_ptr, int* __restrict__ nf,
                             int* __restrict__ nl) {
    int n = blockIdx.x * 256 + threadIdx.x;
    if (n < NN) {
        int b = row_ptr[n] >> 6;
        atomicMin(&nf[b], n);
        atomicMax(&nl[b], n);
    }
}

// ---------------- node MLP (unchanged) ----------------
template <int K1>
__global__ void __launch_bounds__(256, 4)
k_mlp2(const float* __restrict__ A, float* __restrict__ O,
       const float* __restrict__ W1, const float* __restrict__ B1,
       const float* __restrict__ W2, const float* __restrict__ B2, int nrows) {
    constexpr int SA = K1 + 1;
    __shared__ float st[64 * 129];
    const int row0 = blockIdx.x * 64;
    const int tid = threadIdx.x;
    const int tx = tid & 31, ty = tid >> 5, r0 = ty * 8;

    for (int idx = tid; idx < 64 * K1; idx += 256) {
        int r = idx / K1, k = idx - r * K1;
        int row = row0 + r;
        st[r * SA + k] = (row < nrows) ? A[row * K1 + k] : 0.0f;
    }
    __syncthreads();

    float acc[8][4];
#pragma unroll
    for (int i = 0; i < 8; ++i) { acc[i][0] = acc[i][1] = acc[i][2] = acc[i][3] = 0.0f; }
    for (int k = 0; k < K1; ++k) {
        const float4 w = *(const float4*)(W1 + k * H + 4 * tx);
#pragma unroll
        for (int i = 0; i < 8; ++i) {
            float a = st[(r0 + i) * SA + k];
            acc[i][0] = fmaf(a, w.x, acc[i][0]);
            acc[i][1] = fmaf(a, w.y, acc[i][1]);
            acc[i][2] = fmaf(a, w.z, acc[i][2]);
            acc[i][3] = fmaf(a, w.w, acc[i][3]);
        }
    }
    __syncthreads();
    const float4 b1 = *(const float4*)(B1 + 4 * tx);
#pragma unroll
    for (int i = 0; i < 8; ++i) {
        float* p = st + (r0 + i) * 129 + 4 * tx;
        p[0] = gelu_t(acc[i][0] + b1.x);
        p[1] = gelu_t(acc[i][1] + b1.y);
        p[2] = gelu_t(acc[i][2] + b1.z);
        p[3] = gelu_t(acc[i][3] + b1.w);
    }
    __syncthreads();
#pragma unroll
    for (int i = 0; i < 8; ++i) { acc[i][0] = acc[i][1] = acc[i][2] = acc[i][3] = 0.0f; }
    for (int k = 0; k < H; ++k) {
        const float4 w = *(const float4*)(W2 + k * H + 4 * tx);
#pragma unroll
        for (int i = 0; i < 8; ++i) {
            float a = st[(r0 + i) * 129 + k];
            acc[i][0] = fmaf(a, w.x, acc[i][0]);
            acc[i][1] = fmaf(a, w.y, acc[i][1]);
            acc[i][2] = fmaf(a, w.z, acc[i][2]);
            acc[i][3] = fmaf(a, w.w, acc[i][3]);
        }
    }
    const float4 b2 = *(const float4*)(B2 + 4 * tx);
#pragma unroll
    for (int i = 0; i < 8; ++i) {
        int row = row0 + r0 + i;
        if (row < nrows) {
            float4 o;
            o.x = acc[i][0] + b2.x;
            o.y = acc[i][1] + b2.y;
            o.z = acc[i][2] + b2.z;
            o.w = acc[i][3] + b2.w;
            *(float4*)(O + row * H + 4 * tx) = o;
        }
    }
}

// ---------------- fused edge MLP + gather + sorted segment-sum ----------------
// block b owns nodes {n : row_ptr[n]>>6 == b}; processes their edges exclusively.
__global__ void __launch_bounds__(256, 2)
k_edge2(const float* __restrict__ EA, const int* __restrict__ ei,
        const int* __restrict__ perm, const int* __restrict__ row_ptr,
        const int* __restrict__ nf, const int* __restrict__ nl,
        const float* __restrict__ M, float* __restrict__ AGG,
        const float* __restrict__ W1, const float* __restrict__ B1,
        const float* __restrict__ W2, const float* __restrict__ B2) {
    __shared__ int sperm[CAP], ssrc[CAP], sdst[CAP], seg[CAP];
    __shared__ int snode[64];
    __shared__ float sinvd[64];
    __shared__ float sea[64 * ED];
    __shared__ float sh[64 * 129];
    __shared__ float sagg[64 * 132];

    const int b = blockIdx.x;
    const int n0 = nf[b];
    if (n0 >= NN) return;  // sentinel: no nodes in this block
    const int n1 = nl[b];
    const int e0 = row_ptr[n0];
    int ne = row_ptr[n1 + 1] - e0;
    if (ne <= 0) return;  // all deg-0 nodes; agg rows stay memset 0
    const int ncl = (ne < CAP) ? ne : CAP;

    const int tid = threadIdx.x;
    const int tx = tid & 31, ty = tid >> 5, r0 = ty * 8;

    // stage sorted edge ids, src, dst
    {
        int j = tid;
        if (j < ncl) {
            int e = perm[e0 + j];
            sperm[j] = e;
            ssrc[j] = ei[e];
            sdst[j] = ei[NE + e];
        } else {
            sdst[j] = -1 - j;  // unique, never matches
        }
    }
    for (int idx = tid; idx < 64 * 132; idx += 256) sagg[idx] = 0.0f;
    __syncthreads();

    // segment flags + inclusive scan -> segment ids
    int f = 0;
    if (tid < ncl) f = (tid == 0) ? 1 : (sdst[tid] != sdst[tid - 1]);
    seg[tid] = f;
    __syncthreads();
    for (int off = 1; off < 256; off <<= 1) {
        int t = (tid >= off) ? seg[tid - off] : 0;
        __syncthreads();
        seg[tid] += t;
        __syncthreads();
    }
    if (tid < ncl && f) {
        int s = seg[tid] - 1;
        int d = sdst[tid];
        snode[s] = d;
        int deg = row_ptr[d + 1] - row_ptr[d];
        sinvd[s] = 1.0f / (float)deg;
    }
    __syncthreads();
    const int nseg = seg[ncl - 1];

    const int nchunk = (ncl + 63) >> 6;
    const float4 b1v = *(const float4*)(B1 + 4 * tx);
    const float4 b2v = *(const float4*)(B2 + 4 * tx);

    for (int c = 0; c < nchunk; ++c) {
        const int base = c * 64;
        __syncthreads();  // protect sea & sh reuse across chunks
        for (int idx = tid; idx < 64 * ED; idx += 256) {
            int r = idx / ED, k = idx - r * ED;
            int j = base + r;
            sea[idx] = (j < ncl) ? EA[(size_t)sperm[j] * ED + k] : 0.0f;
        }
        __syncthreads();

        float acc[8][4];
#pragma unroll
        for (int i = 0; i < 8; ++i) { acc[i][0] = acc[i][1] = acc[i][2] = acc[i][3] = 0.0f; }
        for (int k = 0; k < ED; ++k) {
            const float4 w = *(const float4*)(W1 + k * H + 4 * tx);
#pragma unroll
            for (int i = 0; i < 8; ++i) {
                float a = sea[(r0 + i) * ED + k];
                acc[i][0] = fmaf(a, w.x, acc[i][0]);
                acc[i][1] = fmaf(a, w.y, acc[i][1]);
                acc[i][2] = fmaf(a, w.z, acc[i][2]);
                acc[i][3] = fmaf(a, w.w, acc[i][3]);
            }
        }
#pragma unroll
        for (int i = 0; i < 8; ++i) {
            float* p = sh + (r0 + i) * 129 + 4 * tx;
            p[0] = gelu_t(acc[i][0] + b1v.x);
            p[1] = gelu_t(acc[i][1] + b1v.y);
            p[2] = gelu_t(acc[i][2] + b1v.z);
            p[3] = gelu_t(acc[i][3] + b1v.w);
        }
        __syncthreads();

#pragma unroll
        for (int i = 0; i < 8; ++i) { acc[i][0] = acc[i][1] = acc[i][2] = acc[i][3] = 0.0f; }
        for (int k = 0; k < H; ++k) {
            const float4 w = *(const float4*)(W2 + k * H + 4 * tx);
#pragma unroll
            for (int i = 0; i < 8; ++i) {
                float a = sh[(r0 + i) * 129 + k];
                acc[i][0] = fmaf(a, w.x, acc[i][0]);
                acc[i][1] = fmaf(a, w.y, acc[i][1]);
                acc[i][2] = fmaf(a, w.z, acc[i][2]);
                acc[i][3] = fmaf(a, w.w, acc[i][3]);
            }
        }

        // msg = ew * m[src]; pre-reduce runs of equal segment, then LDS atomic
        int cs = -1;
        float vx = 0.f, vy = 0.f, vz = 0.f, vw = 0.f;
#pragma unroll
        for (int i = 0; i < 8; ++i) {
            int j = base + r0 + i;
            if (j < ncl) {
                const float4 mv = *(const float4*)(M + (size_t)ssrc[j] * H + 4 * tx);
                float ax = (acc[i][0] + b2v.x) * mv.x;
                float ay = (acc[i][1] + b2v.y) * mv.y;
                float az = (acc[i][2] + b2v.z) * mv.z;
                float aw = (acc[i][3] + b2v.w) * mv.w;
                int s = seg[j] - 1;
                if (s != cs) {
                    if (cs >= 0) {
                        float* p = &sagg[cs * 132 + 4 * tx];
                        atomicAdd(p + 0, vx); atomicAdd(p + 1, vy);
                        atomicAdd(p + 2, vz); atomicAdd(p + 3, vw);
                    }
                    cs = s; vx = ax; vy = ay; vz = az; vw = aw;
                } else {
                    vx += ax; vy += ay; vz += az; vw += aw;
                }
            }
        }
        if (cs >= 0) {
            float* p = &sagg[cs * 132 + 4 * tx];
            atomicAdd(p + 0, vx); atomicAdd(p + 1, vy);
            atomicAdd(p + 2, vz); atomicAdd(p + 3, vw);
        }
    }
    __syncthreads();

    // write mean agg rows (exclusive ownership, coalesced)
    for (int idx = tid; idx < nseg * 32; idx += 256) {
        int s = idx >> 5, q = idx & 31;
        float inv = sinvd[s];
        const float* p = &sagg[s * 132 + 4 * q];
        float4 o;
        o.x = p[0] * inv; o.y = p[1] * inv; o.z = p[2] * inv; o.w = p[3] * inv;
        *(float4*)(AGG + (size_t)snode[s] * H + 4 * q) = o;
    }
}

// ---------------- gate (agg is already mean) ----------------
__global__ void __launch_bounds__(256, 4)
k_gate(const float* __restrict__ HF, const float* __restrict__ AGG,
       const float* __restrict__ GW, const float* __restrict__ GB,
       float* __restrict__ MOUT) {
    __shared__ float st[64 * 129];
    const int row0 = blockIdx.x * 64;
    const int tid = threadIdx.x;
    const int tx = tid & 31, ty = tid >> 5, r0 = ty * 8;

    for (int idx = tid; idx < 64 * H; idx += 256) {
        int r = idx >> 7, k = idx & 127;
        int row = row0 + r;
        st[r * 129 + k] = (row < NN) ? HF[row * H + k] : 0.0f;
    }
    __syncthreads();

    float acc[8][4];
#pragma unroll
    for (int i = 0; i < 8; ++i) { acc[i][0] = acc[i][1] = acc[i][2] = acc[i][3] = 0.0f; }
    for (int k = 0; k < H; ++k) {
        const float4 w = *(const float4*)(GW + k * H + 4 * tx);
#pragma unroll
        for (int i = 0; i < 8; ++i) {
            float a = st[(r0 + i) * 129 + k];
            acc[i][0] = fmaf(a, w.x, acc[i][0]);
            acc[i][1] = fmaf(a, w.y, acc[i][1]);
            acc[i][2] = fmaf(a, w.z, acc[i][2]);
            acc[i][3] = fmaf(a, w.w, acc[i][3]);
        }
    }
    __syncthreads();
    for (int idx = tid; idx < 64 * H; idx += 256) {
        int r = idx >> 7, k = idx & 127;
        int row = row0 + r;
        st[r * 129 + k] = (row < NN) ? AGG[row * H + k] : 0.0f;
    }
    __syncthreads();
    for (int k = 0; k < H; ++k) {
        const float4 w = *(const float4*)(GW + (H + k) * H + 4 * tx);
#pragma unroll
        for (int i = 0; i < 8; ++i) {
            float a = st[(r0 + i) * 129 + k];
            acc[i][0] = fmaf(a, w.x, acc[i][0]);
            acc[i][1] = fmaf(a, w.y, acc[i][1]);
            acc[i][2] = fmaf(a, w.z, acc[i][2]);
            acc[i][3] = fmaf(a, w.w, acc[i][3]);
        }
    }
    const float4 gb = *(const float4*)(GB + 4 * tx);
#pragma unroll
    for (int i = 0; i < 8; ++i) {
        int row = row0 + r0 + i;
        if (row < NN) {
            const float4 hv = *(const float4*)(HF + row * H + 4 * tx);
            const float* ap = st + (r0 + i) * 129 + 4 * tx;
            float4 o;
            o.x = fmaf(sigm(acc[i][0] + gb.x), ap[0], hv.x);
            o.y = fmaf(sigm(acc[i][1] + gb.y), ap[1], hv.y);
            o.z = fmaf(sigm(acc[i][2] + gb.z), ap[2], hv.z);
            o.w = fmaf(sigm(acc[i][3] + gb.w), ap[3], hv.w);
            *(float4*)(MOUT + row * H + 4 * tx) = o;
        }
    }
}

__global__ void k_ln(const float* __restrict__ A, float* __restrict__ O,
                     const float* __restrict__ G, const float* __restrict__ B) {
    int wid = blockIdx.x * 4 + (threadIdx.x >> 6);
    int lane = threadIdx.x & 63;
    if (wid >= NN) return;
    float2 v = *(const float2*)(A + wid * H + 2 * lane);
    float s = v.x + v.y;
#pragma unroll
    for (int o = 32; o > 0; o >>= 1) s += __shfl_xor(s, o);
    float mu = s * (1.0f / 128.0f);
    float dx = v.x - mu, dy = v.y - mu;
    float q = fmaf(dx, dx, dy * dy);
#pragma unroll
    for (int o = 32; o > 0; o >>= 1) q += __shfl_xor(q, o);
    float rs = rsqrtf(q * (1.0f / 128.0f) + 1e-5f);
    float2 g = *(const float2*)(G + 2 * lane);
    float2 b = *(const float2*)(B + 2 * lane);
    float2 ov;
    ov.x = fmaf(dx * rs, g.x, b.x);
    ov.y = fmaf(dy * rs, g.y, b.y);
    *(float2*)(O + wid * H + 2 * lane) = ov;
}

__global__ void k_heads(const float* __restrict__ HF, float* __restrict__ OUT,
                        const float* __restrict__ w1a, const float* __restrict__ b1a,
                        const float* __restrict__ w2a, const float* __restrict__ b2a,
                        const float* __restrict__ w1b, const float* __restrict__ b1b,
                        const float* __restrict__ w2b, const float* __restrict__ b2b,
                        const float* __restrict__ w1c, const float* __restrict__ b1c,
                        const float* __restrict__ w2c, const float* __restrict__ b2c) {
    __shared__ float shh[4 * H];
    int node0 = blockIdx.x * 4;
    int tid = threadIdx.x;
    for (int idx = tid; idx < 4 * H; idx += 256) {
        int row = node0 + (idx >> 7);
        shh[idx] = (row < NN) ? HF[row * H + (idx & 127)] : 0.0f;
    }
    __syncthreads();
    int w = tid >> 6, lane = tid & 63;
    int node = node0 + w;
    if (node >= NN) return;
    const float* hr = shh + w * H;
    const float* w1s[3] = {w1a, w1b, w1c};
    const float* b1s[3] = {b1a, b1b, b1c};
    const float* w2s[3] = {w2a, w2b, w2c};
    const float* b2s[3] = {b2a, b2b, b2c};
#pragma unroll
    for (int t = 0; t < 3; ++t) {
        float a = b1s[t][lane];
        for (int k = 0; k < H; ++k) a = fmaf(hr[k], w1s[t][k * RD + lane], a);
        float p = gelu_t(a) * w2s[t][lane];
#pragma unroll
        for (int o = 32; o > 0; o >>= 1) p += __shfl_xor(p, o);
        if (lane == 0) OUT[t * NN + node] = p + b2s[t][0];
    }
}

extern "C" void kernel_launch(void* const* d_in, const int* in_sizes, int n_in,
                              void* d_out, int out_size, void* d_ws, size_t ws_size,
                              hipStream_t stream) {
    const float* x       = (const float*)d_in[0];
    const int*   ei      = (const int*)d_in[1];
    const float* ea      = (const float*)d_in[2];
    const float* enc_w1  = (const float*)d_in[3];
    const float* enc_b1  = (const float*)d_in[4];
    const float* enc_w2  = (const float*)d_in[5];
    const float* enc_b2  = (const float*)d_in[6];
    const float* edge_w1 = (const float*)d_in[7];
    const float* edge_b1 = (const float*)d_in[8];
    const float* edge_w2 = (const float*)d_in[9];
    const float* edge_b2 = (const float*)d_in[10];
    const float* msg_w1  = (const float*)d_in[11];
    const float* msg_b1  = (const float*)d_in[12];
    const float* msg_w2  = (const float*)d_in[13];
    const float* msg_b2  = (const float*)d_in[14];
    const float* gate_w  = (const float*)d_in[15];
    const float* gate_b  = (const float*)d_in[16];
    const float* ln_g    = (const float*)d_in[17];
    const float* ln_b    = (const float*)d_in[18];
    const float* hw[12];
    for (int t = 0; t < 12; ++t) hw[t] = (const float*)d_in[19 + t];

    const size_t NNH = (size_t)NN * H;
    float* ws   = (float*)d_ws;
    float* h    = ws;
    float* m    = h + NNH;
    float* agg  = m + NNH;
    int* row_ptr = (int*)(agg + NNH);       // NN+1 (pad 100352)
    int* perm    = row_ptr + 100352;        // NE
    int* nf      = perm + NE;               // NB_E (pad 10240)
    int* nl      = nf + 10240;              // NB_E (pad 10240)
    int* hist    = nl + 10240;              // NN (pad 100352)
    int* incl    = hist + 100352;           // NN (pad 100352)
    int* cursor  = incl + 100352;           // NN (pad 100352)
    int* bsum    = cursor + 100352;         // NSB (pad 512)

    // ---- build CSR by dst (per call; deterministic work) ----
    hipMemsetAsync(hist, 0, NN * sizeof(int), stream);
    hipMemsetAsync(nf, 0x7f, NB_E * sizeof(int), stream);
    hipMemsetAsync(nl, 0xff, NB_E * sizeof(int), stream);
    hipMemsetAsync(agg, 0, NNH * sizeof(float), stream);  // covers deg-0 rows

    k_hist<<<(NE + 255) / 256, 256, 0, stream>>>(ei, hist);
    k_scan1<<<NSB, 256, 0, stream>>>(hist, incl, bsum);
    k_scan2<<<1, 512, 0, stream>>>(bsum);
    k_scan3<<<NSB, 256, 0, stream>>>(hist, incl, bsum, row_ptr);
    hipMemcpyAsync(cursor, row_ptr, NN * sizeof(int), hipMemcpyDeviceToDevice, stream);
    k_scatter<<<(NE + 255) / 256, 256, 0, stream>>>(ei, cursor, perm);
    k_blockrange<<<(NN + 255) / 256, 256, 0, stream>>>(row_ptr, nf, nl);

    // ---- network ----
    const int ntiles = (NN + 63) / 64;
    k_mlp2<AD><<<ntiles, 256, 0, stream>>>(x, h, enc_w1, enc_b1, enc_w2, enc_b2, NN);

    for (int l = 0; l < NL; ++l) {
        k_mlp2<H><<<ntiles, 256, 0, stream>>>(h, m,
            msg_w1 + (size_t)l * H * H, msg_b1 + l * H,
            msg_w2 + (size_t)l * H * H, msg_b2 + l * H, NN);
        k_edge2<<<NB_E, 256, 0, stream>>>(ea, ei, perm, row_ptr, nf, nl, m, agg,
            edge_w1 + (size_t)l * ED * H, edge_b1 + l * H,
            edge_w2 + (size_t)l * H * H, edge_b2 + l * H);
        k_gate<<<ntiles, 256, 0, stream>>>(h, agg,
            gate_w + (size_t)l * 2 * H * H, gate_b + l * H, m);
        k_ln<<<(NN + 3) / 4, 256, 0, stream>>>(m, h, ln_g + l * H, ln_b + l * H);
    }

    k_heads<<<(NN + 3) / 4, 256, 0, stream>>>(h, (float*)d_out,
        hw[0], hw[1], hw[2], hw[3],
        hw[4], hw[5], hw[6], hw[7],
        hw[8], hw[9], hw[10], hw[11]);
}

// Round 3
// 3858.258 us; speedup vs baseline: 1.6062x; 1.1408x over previous
//
#include <hip/hip_runtime.h>
#include <math.h>

#define NN 100000
#define NN2 100032               // padded to 64 rows
#define NE 640000
#define H 128
#define AD 25
#define ED 10
#define RD 64
#define NL 4
#define NB_E (NE / 64 + 1)       // 10001 edge blocks
#define NSB ((NN + 255) / 256)   // 391 scan blocks
#define CAP 256

typedef short bfrag __attribute__((ext_vector_type(8)));
typedef float floatx4 __attribute__((ext_vector_type(4)));
typedef unsigned short ushort;

#define MFMA(a, b, c) __builtin_amdgcn_mfma_f32_16x16x32_bf16(a, b, c, 0, 0, 0)

__device__ __forceinline__ ushort f2bf(float f) {
    unsigned u = __float_as_uint(f);
    unsigned r = (u + 0x7FFFu + ((u >> 16) & 1u)) >> 16;
    return (ushort)r;
}
__device__ __forceinline__ float bf2f(ushort b) {
    return __uint_as_float(((unsigned)b) << 16);
}
__device__ __forceinline__ float gelu_t(float x) {
    float u = 0.7978845608028654f * (x + 0.044715f * x * x * x);
    float e = __expf(2.0f * u);
    float th = 1.0f - 2.0f / (e + 1.0f);
    return 0.5f * x * (1.0f + th);
}
__device__ __forceinline__ float sigm(float x) {
    return 1.0f / (1.0f + __expf(-x));
}

// ---------------- weight transpose+convert: dst[b][n][k] = src[b][k][n], zero-pad k>=Ks ----
__global__ void k_wt(const float* __restrict__ src, ushort* __restrict__ dst,
                     int Ks, int N, int Kd, int total) {
    for (int idx = blockIdx.x * 256 + threadIdx.x; idx < total; idx += gridDim.x * 256) {
        int nk = N * Kd;
        int b = idx / nk;
        int rem = idx - b * nk;
        int n = rem / Kd, k = rem - n * Kd;
        float v = (k < Ks) ? src[((size_t)b * Ks + k) * N + n] : 0.0f;
        dst[idx] = f2bf(v);
    }
}
// row-wise convert + K-pad: dst[r][k] = (r<rs && k<Ks) ? src[r][k] : 0
__global__ void k_cvt(const float* __restrict__ src, ushort* __restrict__ dst,
                      int rs, int Ks, int Kd, int total) {
    for (int idx = blockIdx.x * 256 + threadIdx.x; idx < total; idx += gridDim.x * 256) {
        int r = idx / Kd, k = idx - r * Kd;
        dst[idx] = (r < rs && k < Ks) ? f2bf(src[(size_t)r * Ks + k]) : 0;
    }
}

// ---------------- sort infrastructure (unchanged, proven) ----------------
__global__ void k_hist(const int* __restrict__ ei, int* __restrict__ hist) {
    int e = blockIdx.x * 256 + threadIdx.x;
    if (e < NE) atomicAdd(&hist[ei[NE + e]], 1);
}
__global__ void k_scan1(const int* __restrict__ hist, int* __restrict__ incl,
                        int* __restrict__ bsum) {
    __shared__ int s[256];
    int tid = threadIdx.x;
    int i = blockIdx.x * 256 + tid;
    s[tid] = (i < NN) ? hist[i] : 0;
    __syncthreads();
    for (int off = 1; off < 256; off <<= 1) {
        int t = (tid >= off) ? s[tid - off] : 0;
        __syncthreads();
        s[tid] += t;
        __syncthreads();
    }
    if (i < NN) incl[i] = s[tid];
    if (tid == 255) bsum[blockIdx.x] = s[255];
}
__global__ void k_scan2(int* __restrict__ bsum) {
    __shared__ int s[512];
    int tid = threadIdx.x;
    s[tid] = (tid < NSB) ? bsum[tid] : 0;
    __syncthreads();
    for (int off = 1; off < 512; off <<= 1) {
        int t = (tid >= off) ? s[tid - off] : 0;
        __syncthreads();
        s[tid] += t;
        __syncthreads();
    }
    if (tid < NSB) bsum[tid] = (tid > 0) ? s[tid - 1] : 0;
}
__global__ void k_scan3(const int* __restrict__ hist, const int* __restrict__ incl,
                        const int* __restrict__ bsum, int* __restrict__ row_ptr) {
    int i = blockIdx.x * 256 + threadIdx.x;
    if (i < NN) row_ptr[i] = bsum[blockIdx.x] + incl[i] - hist[i];
    if (i == 0) row_ptr[NN] = NE;
}
__global__ void k_scatter(const int* __restrict__ ei, int* __restrict__ cursor,
                          int* __restrict__ perm) {
    int e = blockIdx.x * 256 + threadIdx.x;
    if (e < NE) {
        int d = ei[NE + e];
        int pos = atomicAdd(&cursor[d], 1);
        perm[pos] = e;
    }
}
__global__ void k_blockrange(const int* __restrict__ row_ptr, int* __restrict__ nf,
                             int* __restrict__ nl) {
    int n = blockIdx.x * 256 + threadIdx.x;
    if (n < NN) {
        int b = row_ptr[n] >> 6;
        atomicMin(&nf[b], n);
        atomicMax(&nl[b], n);
    }
}

// ---------------- MFMA node MLP2: O = gelu(A@W1+b1)@W2+b2 ----------------
// swapped G1 (A=W1t, B=input) -> LDS transpose -> normal G2.
template <int K1, int WH>   // WH=1: also write f32 copy (encoder)
__global__ void __launch_bounds__(256)
k_mlp2mf(const ushort* __restrict__ Abf, ushort* __restrict__ Obf, float* __restrict__ Of32,
         const ushort* __restrict__ W1t, const float* __restrict__ B1,
         const ushort* __restrict__ W2t, const float* __restrict__ B2) {
    __shared__ ushort sH[64 * 136];
    const int tid = threadIdx.x;
    const int w = tid >> 6, lane = tid & 63, lr = lane & 15, lg = lane >> 4;
    const int rowB = blockIdx.x * 64 + w * 16 + lr;

    floatx4 acc[8];
#pragma unroll
    for (int t = 0; t < 8; ++t) acc[t] = (floatx4){0.f, 0.f, 0.f, 0.f};
#pragma unroll
    for (int kb = 0; kb < K1 / 32; ++kb) {
        bfrag bv = *(const bfrag*)(Abf + (size_t)rowB * K1 + kb * 32 + lg * 8);
#pragma unroll
        for (int t = 0; t < 8; ++t) {
            bfrag av = *(const bfrag*)(W1t + (t * 16 + lr) * K1 + kb * 32 + lg * 8);
            acc[t] = MFMA(av, bv, acc[t]);
        }
    }
    ushort* sHrow = sH + (w * 16 + lr) * 136;
#pragma unroll
    for (int t = 0; t < 8; ++t) {
        const float4 b1 = *(const float4*)(B1 + t * 16 + lg * 4);
        float h0 = gelu_t(acc[t][0] + b1.x), h1 = gelu_t(acc[t][1] + b1.y);
        float h2 = gelu_t(acc[t][2] + b1.z), h3 = gelu_t(acc[t][3] + b1.w);
        uint2 p;
        p.x = (unsigned)f2bf(h0) | ((unsigned)f2bf(h1) << 16);
        p.y = (unsigned)f2bf(h2) | ((unsigned)f2bf(h3) << 16);
        *(uint2*)(sHrow + t * 16 + lg * 4) = p;
    }
#pragma unroll
    for (int t = 0; t < 8; ++t) acc[t] = (floatx4){0.f, 0.f, 0.f, 0.f};
#pragma unroll
    for (int kb = 0; kb < 4; ++kb) {
        bfrag av = *(const bfrag*)(sH + (w * 16 + lr) * 136 + kb * 32 + lg * 8);
#pragma unroll
        for (int t = 0; t < 8; ++t) {
            bfrag bv = *(const bfrag*)(W2t + (t * 16 + lr) * 128 + kb * 32 + lg * 8);
            acc[t] = MFMA(av, bv, acc[t]);
        }
    }
    const int rowD = blockIdx.x * 64 + w * 16 + lg * 4;
#pragma unroll
    for (int t = 0; t < 8; ++t) {
        const int col = t * 16 + lr;
        const float b2 = B2[col];
#pragma unroll
        for (int r = 0; r < 4; ++r) {
            int row = rowD + r;
            if (row < NN) {
                float v = acc[t][r] + b2;
                Obf[(size_t)row * 128 + col] = f2bf(v);
                if (WH) Of32[(size_t)row * 128 + col] = v;
            }
        }
    }
}

// ---------------- edge: MFMA MLP2(ea) * m[src] -> sorted segment mean ----------------
__global__ void __launch_bounds__(256)
k_edgemf(const ushort* __restrict__ eabf, const int* __restrict__ ei,
         const int* __restrict__ perm, const int* __restrict__ row_ptr,
         const int* __restrict__ nf, const int* __restrict__ nl,
         const ushort* __restrict__ mbf, ushort* __restrict__ aggbf,
         const ushort* __restrict__ W1t, const float* __restrict__ B1,
         const ushort* __restrict__ W2t, const float* __restrict__ B2) {
    __shared__ int ssrc[CAP], sdst[CAP], sseg[CAP];
    __shared__ int snode[64];
    __shared__ float sinvd[64];
    __shared__ ushort sea[64 * 40];
    __shared__ ushort sH[64 * 136];
    __shared__ float sagg[64 * 132];
    __shared__ int swtot[4];
    __shared__ int s_nseg;

    const int b = blockIdx.x;
    const int n0 = nf[b];
    if (n0 >= NN) return;
    const int n1 = nl[b];
    const int e0 = row_ptr[n0];
    int ne = row_ptr[n1 + 1] - e0;
    if (ne <= 0) return;
    const int ncl = (ne < CAP) ? ne : CAP;

    const int tid = threadIdx.x;
    const int w = tid >> 6, lane = tid & 63, lr = lane & 15, lg = lane >> 4;

    for (int i = tid; i < 64 * 132; i += 256) sagg[i] = 0.0f;
    for (int i = tid; i < 64 * 16; i += 256) sea[(i >> 4) * 40 + 16 + (i & 15)] = 0;

    int dstv = -1 - tid;
    if (tid < ncl) {
        int e = perm[e0 + tid];
        ssrc[tid] = ei[e];
        dstv = ei[NE + e];
    }
    sdst[tid] = dstv;
    __syncthreads();

    int f = 0;
    if (tid < ncl) f = (tid == 0) ? 1 : (sdst[tid] != sdst[tid - 1]);
    unsigned long long mk = __ballot(f);
    int incl = __popcll(mk & (~0ull >> (63 - lane)));
    if (lane == 63) swtot[w] = incl;
    __syncthreads();
    int woff = 0;
    for (int i = 0; i < w; ++i) woff += swtot[i];
    int segid = woff + incl;
    sseg[tid] = segid - 1;
    if (f) {
        int s = segid - 1;
        snode[s] = dstv;
        sinvd[s] = 1.0f / (float)(row_ptr[dstv + 1] - row_ptr[dstv]);
    }
    if (tid == 255) s_nseg = segid;
    __syncthreads();
    const int nseg = s_nseg;
    const int nchunk = (ncl + 63) >> 6;

    for (int c = 0; c < nchunk; ++c) {
        const int base = c * 64;
        if (c > 0) __syncthreads();
        for (int i = tid; i < 128; i += 256) {
            int r = i >> 1, hf_ = i & 1;
            int j = base + r;
            if (j < ncl) {
                int e = perm[e0 + j];
                *(uint4*)(sea + r * 40 + hf_ * 8) =
                    *(const uint4*)(eabf + (size_t)e * 16 + hf_ * 8);
            }
        }
        __syncthreads();

        // G1 swapped: hidden[row][hc], K=32 (10 real)
        floatx4 acc[8];
#pragma unroll
        for (int t = 0; t < 8; ++t) acc[t] = (floatx4){0.f, 0.f, 0.f, 0.f};
        {
            bfrag bv = *(const bfrag*)(sea + (w * 16 + lr) * 40 + lg * 8);
#pragma unroll
            for (int t = 0; t < 8; ++t) {
                bfrag av = *(const bfrag*)(W1t + (t * 16 + lr) * 32 + lg * 8);
                acc[t] = MFMA(av, bv, acc[t]);
            }
        }
        ushort* sHrow = sH + (w * 16 + lr) * 136;
#pragma unroll
        for (int t = 0; t < 8; ++t) {
            const float4 b1 = *(const float4*)(B1 + t * 16 + lg * 4);
            float h0 = gelu_t(acc[t][0] + b1.x), h1 = gelu_t(acc[t][1] + b1.y);
            float h2 = gelu_t(acc[t][2] + b1.z), h3 = gelu_t(acc[t][3] + b1.w);
            uint2 p;
            p.x = (unsigned)f2bf(h0) | ((unsigned)f2bf(h1) << 16);
            p.y = (unsigned)f2bf(h2) | ((unsigned)f2bf(h3) << 16);
            *(uint2*)(sHrow + t * 16 + lg * 4) = p;
        }
        // G2 normal
#pragma unroll
        for (int t = 0; t < 8; ++t) acc[t] = (floatx4){0.f, 0.f, 0.f, 0.f};
#pragma unroll
        for (int kb = 0; kb < 4; ++kb) {
            bfrag av = *(const bfrag*)(sH + (w * 16 + lr) * 136 + kb * 32 + lg * 8);
#pragma unroll
            for (int t = 0; t < 8; ++t) {
                bfrag bv = *(const bfrag*)(W2t + (t * 16 + lr) * 128 + kb * 32 + lg * 8);
                acc[t] = MFMA(av, bv, acc[t]);
            }
        }
        // epilogue: ew*m[src] -> segment pre-reduce -> LDS atomic
        int sg[4], sr[4];
#pragma unroll
        for (int r = 0; r < 4; ++r) {
            int j = base + w * 16 + lg * 4 + r;
            if (j < ncl) { sg[r] = sseg[j]; sr[r] = ssrc[j]; }
            else { sg[r] = -1; sr[r] = 0; }
        }
#pragma unroll
        for (int t = 0; t < 8; ++t) {
            const int col = t * 16 + lr;
            const float b2 = B2[col];
            int cs = -1;
            float cv = 0.0f;
#pragma unroll
            for (int r = 0; r < 4; ++r) {
                if (sg[r] >= 0) {
                    float mval = bf2f(mbf[(size_t)sr[r] * 128 + col]);
                    float v = (acc[t][r] + b2) * mval;
                    if (sg[r] != cs) {
                        if (cs >= 0) atomicAdd(&sagg[cs * 132 + col], cv);
                        cs = sg[r];
                        cv = v;
                    } else {
                        cv += v;
                    }
                }
            }
            if (cs >= 0) atomicAdd(&sagg[cs * 132 + col], cv);
        }
    }
    __syncthreads();
    for (int i = tid; i < nseg * 32; i += 256) {
        int s = i >> 5, qd = i & 31;
        float inv = sinvd[s];
        const float* p = &sagg[s * 132 + qd * 4];
        float vx = p[0] * inv, vy = p[1] * inv, vz = p[2] * inv, vw = p[3] * inv;
        uint2 pk;
        pk.x = (unsigned)f2bf(vx) | ((unsigned)f2bf(vy) << 16);
        pk.y = (unsigned)f2bf(vz) | ((unsigned)f2bf(vw) << 16);
        *(uint2*)(aggbf + (size_t)snode[s] * 128 + qd * 4) = pk;
    }
}

// ---------------- gate + residual + LayerNorm, fused, no LDS ----------------
__global__ void __launch_bounds__(256)
k_gateln(ushort* __restrict__ hbf, const ushort* __restrict__ aggbf,
         float* __restrict__ hf,
         const ushort* __restrict__ GWt, const float* __restrict__ GB,
         const float* __restrict__ LNG, const float* __restrict__ LNB) {
    const int tid = threadIdx.x;
    const int w = tid >> 6, lane = tid & 63, lr = lane & 15, lg = lane >> 4;
    const int row = blockIdx.x * 64 + w * 16 + lr;

    floatx4 acc[8];
#pragma unroll
    for (int t = 0; t < 8; ++t) acc[t] = (floatx4){0.f, 0.f, 0.f, 0.f};
#pragma unroll
    for (int kb = 0; kb < 8; ++kb) {
        bfrag bv;
        if (kb < 4) bv = *(const bfrag*)(hbf + (size_t)row * 128 + kb * 32 + lg * 8);
        else bv = *(const bfrag*)(aggbf + (size_t)row * 128 + (kb - 4) * 32 + lg * 8);
#pragma unroll
        for (int t = 0; t < 8; ++t) {
            bfrag av = *(const bfrag*)(GWt + (t * 16 + lr) * 256 + kb * 32 + lg * 8);
            acc[t] = MFMA(av, bv, acc[t]);
        }
    }
    float o[8][4];
    float s = 0.0f;
#pragma unroll
    for (int t = 0; t < 8; ++t) {
        const int c0 = t * 16 + lg * 4;
        const float4 gb = *(const float4*)(GB + c0);
        const float4 hv = *(const float4*)(hf + (size_t)row * 128 + c0);
        // agg bf16 unpack (4 vals = uint2)
        uint2 ap = *(const uint2*)(aggbf + (size_t)row * 128 + c0);
        float a0 = bf2f((ushort)(ap.x & 0xFFFF)), a1 = bf2f((ushort)(ap.x >> 16));
        float a2 = bf2f((ushort)(ap.y & 0xFFFF)), a3 = bf2f((ushort)(ap.y >> 16));
        o[t][0] = hv.x + sigm(acc[t][0] + gb.x) * a0;
        o[t][1] = hv.y + sigm(acc[t][1] + gb.y) * a1;
        o[t][2] = hv.z + sigm(acc[t][2] + gb.z) * a2;
        o[t][3] = hv.w + sigm(acc[t][3] + gb.w) * a3;
        s += o[t][0] + o[t][1] + o[t][2] + o[t][3];
    }
    s += __shfl_xor(s, 16);
    s += __shfl_xor(s, 32);
    const float mu = s * (1.0f / 128.0f);
    float q = 0.0f;
#pragma unroll
    for (int t = 0; t < 8; ++t)
#pragma unroll
        for (int r = 0; r < 4; ++r) {
            float dx = o[t][r] - mu;
            q = fmaf(dx, dx, q);
        }
    q += __shfl_xor(q, 16);
    q += __shfl_xor(q, 32);
    const float rs = rsqrtf(q * (1.0f / 128.0f) + 1e-5f);

    if (row < NN) {
#pragma unroll
        for (int t = 0; t < 8; ++t) {
            const int c0 = t * 16 + lg * 4;
            const float4 g4 = *(const float4*)(LNG + c0);
            const float4 b4 = *(const float4*)(LNB + c0);
            float4 res;
            res.x = fmaf((o[t][0] - mu) * rs, g4.x, b4.x);
            res.y = fmaf((o[t][1] - mu) * rs, g4.y, b4.y);
            res.z = fmaf((o[t][2] - mu) * rs, g4.z, b4.z);
            res.w = fmaf((o[t][3] - mu) * rs, g4.w, b4.w);
            *(float4*)(hf + (size_t)row * 128 + c0) = res;
            uint2 pk;
            pk.x = (unsigned)f2bf(res.x) | ((unsigned)f2bf(res.y) << 16);
            pk.y = (unsigned)f2bf(res.z) | ((unsigned)f2bf(res.w) << 16);
            *(uint2*)(hbf + (size_t)row * 128 + c0) = pk;
        }
    }
}

// ---------------- heads: one swapped MFMA GEMM over concat [192,128] + dot ----------------
__global__ void __launch_bounds__(256)
k_headsmf(const ushort* __restrict__ hbf, float* __restrict__ OUT,
          const ushort* __restrict__ WHt,
          const float* __restrict__ b1a, const float* __restrict__ b1b, const float* __restrict__ b1c,
          const float* __restrict__ w2a, const float* __restrict__ w2b, const float* __restrict__ w2c,
          const float* __restrict__ b2a, const float* __restrict__ b2b, const float* __restrict__ b2c) {
    const int tid = threadIdx.x;
    const int w = tid >> 6, lane = tid & 63, lr = lane & 15, lg = lane >> 4;
    const int row = blockIdx.x * 64 + w * 16 + lr;

    floatx4 acc[12];
#pragma unroll
    for (int t = 0; t < 12; ++t) acc[t] = (floatx4){0.f, 0.f, 0.f, 0.f};
#pragma unroll
    for (int kb = 0; kb < 4; ++kb) {
        bfrag bv = *(const bfrag*)(hbf + (size_t)row * 128 + kb * 32 + lg * 8);
#pragma unroll
        for (int t = 0; t < 12; ++t) {
            bfrag av = *(const bfrag*)(WHt + (t * 16 + lr) * 128 + kb * 32 + lg * 8);
            acc[t] = MFMA(av, bv, acc[t]);
        }
    }
    const float* b1s[3] = {b1a, b1b, b1c};
    const float* w2s[3] = {w2a, w2b, w2c};
    float p[3] = {0.f, 0.f, 0.f};
#pragma unroll
    for (int t = 0; t < 12; ++t) {
        const int head = t >> 2;
        const int c0 = (t & 3) * 16 + lg * 4;
        const float4 b1 = *(const float4*)(b1s[head] + c0);
        const float4 w2 = *(const float4*)(w2s[head] + c0);
        p[head] += gelu_t(acc[t][0] + b1.x) * w2.x;
        p[head] += gelu_t(acc[t][1] + b1.y) * w2.y;
        p[head] += gelu_t(acc[t][2] + b1.z) * w2.z;
        p[head] += gelu_t(acc[t][3] + b1.w) * w2.w;
    }
#pragma unroll
    for (int hd = 0; hd < 3; ++hd) {
        p[hd] += __shfl_xor(p[hd], 16);
        p[hd] += __shfl_xor(p[hd], 32);
    }
    if (lg == 0 && row < NN) {
        OUT[0 * NN + row] = p[0] + b2a[0];
        OUT[1 * NN + row] = p[1] + b2b[0];
        OUT[2 * NN + row] = p[2] + b2c[0];
    }
}

extern "C" void kernel_launch(void* const* d_in, const int* in_sizes, int n_in,
                              void* d_out, int out_size, void* d_ws, size_t ws_size,
                              hipStream_t stream) {
    const float* x       = (const float*)d_in[0];
    const int*   ei      = (const int*)d_in[1];
    const float* ea      = (const float*)d_in[2];
    const float* enc_w1  = (const float*)d_in[3];
    const float* enc_b1  = (const float*)d_in[4];
    const float* enc_w2  = (const float*)d_in[5];
    const float* enc_b2  = (const float*)d_in[6];
    const float* edge_w1 = (const float*)d_in[7];
    const float* edge_b1 = (const float*)d_in[8];
    const float* edge_w2 = (const float*)d_in[9];
    const float* edge_b2 = (const float*)d_in[10];
    const float* msg_w1  = (const float*)d_in[11];
    const float* msg_b1  = (const float*)d_in[12];
    const float* msg_w2  = (const float*)d_in[13];
    const float* msg_b2  = (const float*)d_in[14];
    const float* gate_w  = (const float*)d_in[15];
    const float* gate_b  = (const float*)d_in[16];
    const float* ln_g    = (const float*)d_in[17];
    const float* ln_b    = (const float*)d_in[18];
    const float* hw[12];
    for (int t = 0; t < 12; ++t) hw[t] = (const float*)d_in[19 + t];

    const size_t NNH = (size_t)NN2 * H;
    float*  ws    = (float*)d_ws;
    float*  hf    = ws;                          // NNH f32
    ushort* hbf   = (ushort*)(hf + NNH);         // NNH bf16
    ushort* mbf   = hbf + NNH;                   // NNH bf16
    ushort* aggbf = mbf + NNH;                   // NNH bf16
    ushort* xbf   = aggbf + NNH;                 // NN2*32 bf16
    ushort* eabf  = xbf + (size_t)NN2 * 32;      // NE*16 bf16
    ushort* wt    = eabf + (size_t)NE * 16;      // weights, bf16
    ushort* wt_enc1 = wt;                        // 128*32
    ushort* wt_enc2 = wt_enc1 + 128 * 32;        // 128*128
    ushort* wt_e1   = wt_enc2 + 128 * 128;       // 4*128*32
    ushort* wt_e2   = wt_e1 + 4 * 128 * 32;      // 4*128*128
    ushort* wt_m1   = wt_e2 + 4 * 128 * 128;     // 4*128*128
    ushort* wt_m2   = wt_m1 + 4 * 128 * 128;     // 4*128*128
    ushort* wt_g    = wt_m2 + 4 * 128 * 128;     // 4*128*256
    ushort* wt_h    = wt_g + 4 * 128 * 256;      // 192*128
    int* row_ptr = (int*)(wt_h + 192 * 128 + 64);
    int* perm    = row_ptr + 100352;
    int* nf      = perm + NE;
    int* nl      = nf + 10240;
    int* hist    = nl + 10240;
    int* incl    = hist + 100352;
    int* cursor  = incl + 100352;
    int* bsum    = cursor + 100352;

    // ---- converts (once per call) ----
    k_wt<<<64, 256, 0, stream>>>(enc_w1, wt_enc1, 25, 128, 32, 128 * 32);
    k_wt<<<64, 256, 0, stream>>>(enc_w2, wt_enc2, 128, 128, 128, 128 * 128);
    k_wt<<<64, 256, 0, stream>>>(edge_w1, wt_e1, 10, 128, 32, 4 * 128 * 32);
    k_wt<<<256, 256, 0, stream>>>(edge_w2, wt_e2, 128, 128, 128, 4 * 128 * 128);
    k_wt<<<256, 256, 0, stream>>>(msg_w1, wt_m1, 128, 128, 128, 4 * 128 * 128);
    k_wt<<<256, 256, 0, stream>>>(msg_w2, wt_m2, 128, 128, 128, 4 * 128 * 128);
    k_wt<<<512, 256, 0, stream>>>(gate_w, wt_g, 256, 128, 256, 4 * 128 * 256);
    k_wt<<<32, 256, 0, stream>>>(hw[0], wt_h, 128, 64, 128, 64 * 128);
    k_wt<<<32, 256, 0, stream>>>(hw[4], wt_h + 64 * 128, 128, 64, 128, 64 * 128);
    k_wt<<<32, 256, 0, stream>>>(hw[8], wt_h + 128 * 128, 128, 64, 128, 64 * 128);
    k_cvt<<<3200, 256, 0, stream>>>(x, xbf, NN, 25, 32, NN2 * 32);
    k_cvt<<<8192, 256, 0, stream>>>(ea, eabf, NE, 10, 16, NE * 16);

    // ---- sort by dst ----
    hipMemsetAsync(hist, 0, NN * sizeof(int), stream);
    hipMemsetAsync(nf, 0x7f, NB_E * sizeof(int), stream);
    hipMemsetAsync(nl, 0xff, NB_E * sizeof(int), stream);
    hipMemsetAsync(aggbf, 0, NNH * sizeof(ushort), stream);
    k_hist<<<(NE + 255) / 256, 256, 0, stream>>>(ei, hist);
    k_scan1<<<NSB, 256, 0, stream>>>(hist, incl, bsum);
    k_scan2<<<1, 512, 0, stream>>>(bsum);
    k_scan3<<<NSB, 256, 0, stream>>>(hist, incl, bsum, row_ptr);
    hipMemcpyAsync(cursor, row_ptr, NN * sizeof(int), hipMemcpyDeviceToDevice, stream);
    k_scatter<<<(NE + 255) / 256, 256, 0, stream>>>(ei, cursor, perm);
    k_blockrange<<<(NN + 255) / 256, 256, 0, stream>>>(row_ptr, nf, nl);

    // ---- network ----
    const int ntiles = NN2 / 64;
    k_mlp2mf<32, 1><<<ntiles, 256, 0, stream>>>(xbf, hbf, hf,
        wt_enc1, enc_b1, wt_enc2, enc_b2);

    for (int l = 0; l < NL; ++l) {
        k_mlp2mf<128, 0><<<ntiles, 256, 0, stream>>>(hbf, mbf, nullptr,
            wt_m1 + (size_t)l * 128 * 128, msg_b1 + l * H,
            wt_m2 + (size_t)l * 128 * 128, msg_b2 + l * H);
        k_edgemf<<<NB_E, 256, 0, stream>>>(eabf, ei, perm, row_ptr, nf, nl, mbf, aggbf,
            wt_e1 + (size_t)l * 128 * 32, edge_b1 + l * H,
            wt_e2 + (size_t)l * 128 * 128, edge_b2 + l * H);
        k_gateln<<<ntiles, 256, 0, stream>>>(hbf, aggbf, hf,
            wt_g + (size_t)l * 128 * 256, gate_b + l * H,
            ln_g + l * H, ln_b + l * H);
    }

    k_headsmf<<<ntiles, 256, 0, stream>>>(hbf, (float*)d_out, wt_h,
        hw[1], hw[5], hw[9], hw[2], hw[6], hw[10], hw[3], hw[7], hw[11]);
}

// Round 4
// 2771.623 us; speedup vs baseline: 2.2359x; 1.3921x over previous
//
#include <hip/hip_runtime.h>
#include <math.h>

#define NN 100000
#define NN2 100032               // padded to 64 rows
#define NE 640000
#define H 128
#define AD 25
#define ED 10
#define RD 64
#define NL 4
#define NB_E (NE / 64 + 1)       // 10001 edge blocks
#define NSB ((NN + 255) / 256)   // 391 scan blocks
#define CAP 256
#define PART_E 160000            // edges per part (64-group aligned)
#define PART_ROWS 161024         // PART_E + 1024 overlap
#define PART_BLK (PART_ROWS / 128)  // 1258
#define PART_GB 2500             // edge-groups (blocks of k_gms) per part

typedef short bfrag __attribute__((ext_vector_type(8)));
typedef float floatx4 __attribute__((ext_vector_type(4)));
typedef unsigned short ushort;

#define MFMA(a, b, c) __builtin_amdgcn_mfma_f32_16x16x32_bf16(a, b, c, 0, 0, 0)

__device__ __forceinline__ ushort f2bf(float f) {
    unsigned u = __float_as_uint(f);
    unsigned r = (u + 0x7FFFu + ((u >> 16) & 1u)) >> 16;
    return (ushort)r;
}
__device__ __forceinline__ float bf2f(ushort b) {
    return __uint_as_float(((unsigned)b) << 16);
}
__device__ __forceinline__ float gelu_t(float x) {
    float u = 0.7978845608028654f * (x + 0.044715f * x * x * x);
    float e = __expf(2.0f * u);
    float th = 1.0f - 2.0f / (e + 1.0f);
    return 0.5f * x * (1.0f + th);
}
__device__ __forceinline__ float sigm(float x) {
    return 1.0f / (1.0f + __expf(-x));
}

// ---------------- weight transpose+convert: dst[b][n][k] = src[b][k][n], zero-pad k>=Ks ----
__global__ void k_wt(const float* __restrict__ src, ushort* __restrict__ dst,
                     int Ks, int N, int Kd, int total) {
    for (int idx = blockIdx.x * 256 + threadIdx.x; idx < total; idx += gridDim.x * 256) {
        int nk = N * Kd;
        int b = idx / nk;
        int rem = idx - b * nk;
        int n = rem / Kd, k = rem - n * Kd;
        float v = (k < Ks) ? src[((size_t)b * Ks + k) * N + n] : 0.0f;
        dst[idx] = f2bf(v);
    }
}
// row-wise convert + K-pad
__global__ void k_cvt(const float* __restrict__ src, ushort* __restrict__ dst,
                      int rs, int Ks, int Kd, int total) {
    for (int idx = blockIdx.x * 256 + threadIdx.x; idx < total; idx += gridDim.x * 256) {
        int r = idx / Kd, k = idx - r * Kd;
        dst[idx] = (r < rs && k < Ks) ? f2bf(src[(size_t)r * Ks + k]) : 0;
    }
}
// permuted edge-attr convert: out[j] = bf16(ea[perm[j]]), K-padded 10->16
__global__ void k_cvtperm(const float* __restrict__ ea, const int* __restrict__ perm,
                          ushort* __restrict__ out) {
    int j = blockIdx.x * 256 + threadIdx.x;
    if (j >= NE) return;
    const float* src = ea + (size_t)perm[j] * ED;
    unsigned u[8];
#pragma unroll
    for (int k = 0; k < 5; ++k)
        u[k] = (unsigned)f2bf(src[2 * k]) | ((unsigned)f2bf(src[2 * k + 1]) << 16);
    u[5] = u[6] = u[7] = 0u;
    uint4* o = (uint4*)(out + (size_t)j * 16);
    uint4 a; a.x = u[0]; a.y = u[1]; a.z = u[2]; a.w = u[3];
    uint4 b; b.x = u[4]; b.y = u[5]; b.z = u[6]; b.w = u[7];
    o[0] = a; o[1] = b;
}

// ---------------- sort infrastructure (unchanged, proven) ----------------
__global__ void k_hist(const int* __restrict__ ei, int* __restrict__ hist) {
    int e = blockIdx.x * 256 + threadIdx.x;
    if (e < NE) atomicAdd(&hist[ei[NE + e]], 1);
}
__global__ void k_scan1(const int* __restrict__ hist, int* __restrict__ incl,
                        int* __restrict__ bsum) {
    __shared__ int s[256];
    int tid = threadIdx.x;
    int i = blockIdx.x * 256 + tid;
    s[tid] = (i < NN) ? hist[i] : 0;
    __syncthreads();
    for (int off = 1; off < 256; off <<= 1) {
        int t = (tid >= off) ? s[tid - off] : 0;
        __syncthreads();
        s[tid] += t;
        __syncthreads();
    }
    if (i < NN) incl[i] = s[tid];
    if (tid == 255) bsum[blockIdx.x] = s[255];
}
__global__ void k_scan2(int* __restrict__ bsum) {
    __shared__ int s[512];
    int tid = threadIdx.x;
    s[tid] = (tid < NSB) ? bsum[tid] : 0;
    __syncthreads();
    for (int off = 1; off < 512; off <<= 1) {
        int t = (tid >= off) ? s[tid - off] : 0;
        __syncthreads();
        s[tid] += t;
        __syncthreads();
    }
    if (tid < NSB) bsum[tid] = (tid > 0) ? s[tid - 1] : 0;
}
__global__ void k_scan3(const int* __restrict__ hist, const int* __restrict__ incl,
                        const int* __restrict__ bsum, int* __restrict__ row_ptr) {
    int i = blockIdx.x * 256 + threadIdx.x;
    if (i < NN) row_ptr[i] = bsum[blockIdx.x] + incl[i] - hist[i];
    if (i == 0) row_ptr[NN] = NE;
}
__global__ void k_scatter(const int* __restrict__ ei, int* __restrict__ cursor,
                          int* __restrict__ perm) {
    int e = blockIdx.x * 256 + threadIdx.x;
    if (e < NE) {
        int d = ei[NE + e];
        int pos = atomicAdd(&cursor[d], 1);
        perm[pos] = e;
    }
}
__global__ void k_blockrange(const int* __restrict__ row_ptr, int* __restrict__ nf,
                             int* __restrict__ nl) {
    int n = blockIdx.x * 256 + threadIdx.x;
    if (n < NN) {
        int b = row_ptr[n] >> 6;
        atomicMin(&nf[b], n);
        atomicMax(&nl[b], n);
    }
}

// ---------------- MFMA node MLP2 (proven) ----------------
template <int K1, int WH>
__global__ void __launch_bounds__(256)
k_mlp2mf(const ushort* __restrict__ Abf, ushort* __restrict__ Obf, float* __restrict__ Of32,
         const ushort* __restrict__ W1t, const float* __restrict__ B1,
         const ushort* __restrict__ W2t, const float* __restrict__ B2) {
    __shared__ ushort sH[64 * 136];
    const int tid = threadIdx.x;
    const int w = tid >> 6, lane = tid & 63, lr = lane & 15, lg = lane >> 4;
    const int rowB = blockIdx.x * 64 + w * 16 + lr;

    floatx4 acc[8];
#pragma unroll
    for (int t = 0; t < 8; ++t) acc[t] = (floatx4){0.f, 0.f, 0.f, 0.f};
#pragma unroll
    for (int kb = 0; kb < K1 / 32; ++kb) {
        bfrag bv = *(const bfrag*)(Abf + (size_t)rowB * K1 + kb * 32 + lg * 8);
#pragma unroll
        for (int t = 0; t < 8; ++t) {
            bfrag av = *(const bfrag*)(W1t + (t * 16 + lr) * K1 + kb * 32 + lg * 8);
            acc[t] = MFMA(av, bv, acc[t]);
        }
    }
    ushort* sHrow = sH + (w * 16 + lr) * 136;
#pragma unroll
    for (int t = 0; t < 8; ++t) {
        const float4 b1 = *(const float4*)(B1 + t * 16 + lg * 4);
        float h0 = gelu_t(acc[t][0] + b1.x), h1 = gelu_t(acc[t][1] + b1.y);
        float h2 = gelu_t(acc[t][2] + b1.z), h3 = gelu_t(acc[t][3] + b1.w);
        uint2 p;
        p.x = (unsigned)f2bf(h0) | ((unsigned)f2bf(h1) << 16);
        p.y = (unsigned)f2bf(h2) | ((unsigned)f2bf(h3) << 16);
        *(uint2*)(sHrow + t * 16 + lg * 4) = p;
    }
#pragma unroll
    for (int t = 0; t < 8; ++t) acc[t] = (floatx4){0.f, 0.f, 0.f, 0.f};
#pragma unroll
    for (int kb = 0; kb < 4; ++kb) {
        bfrag av = *(const bfrag*)(sH + (w * 16 + lr) * 136 + kb * 32 + lg * 8);
#pragma unroll
        for (int t = 0; t < 8; ++t) {
            bfrag bv = *(const bfrag*)(W2t + (t * 16 + lr) * 128 + kb * 32 + lg * 8);
            acc[t] = MFMA(av, bv, acc[t]);
        }
    }
    const int rowD = blockIdx.x * 64 + w * 16 + lg * 4;
#pragma unroll
    for (int t = 0; t < 8; ++t) {
        const int col = t * 16 + lr;
        const float b2 = B2[col];
#pragma unroll
        for (int r = 0; r < 4; ++r) {
            int row = rowD + r;
            if (row < NN) {
                float v = acc[t][r] + b2;
                Obf[(size_t)row * 128 + col] = f2bf(v);
                if (WH) Of32[(size_t)row * 128 + col] = v;
            }
        }
    }
}

// ---------------- A: edge-weight GEMM over sorted edges, coalesced output ----------------
__global__ void __launch_bounds__(256)
k_ew(const ushort* __restrict__ eap, ushort* __restrict__ ewp, int S,
     const ushort* __restrict__ W1t, const float* __restrict__ B1,
     const ushort* __restrict__ W2t, const float* __restrict__ B2) {
    __shared__ ushort sea[128 * 40];
    __shared__ ushort sH[4][16 * 136];
    const int tid = threadIdx.x;
    const int w = tid >> 6, lane = tid & 63, lr = lane & 15, lg = lane >> 4;
    const int jl0 = blockIdx.x * 128;   // part-local base row

    {
        int r = tid >> 1, half = tid & 1;
        int j = S + jl0 + r;
        uint4 z; z.x = z.y = z.z = z.w = 0u;
        uint4 v = z;
        if (j < NE) v = *(const uint4*)(eap + (size_t)j * 16 + half * 8);
        *(uint4*)(sea + r * 40 + half * 8) = v;
        *(uint4*)(sea + r * 40 + 16 + half * 8) = z;
    }
    __syncthreads();

    for (int rt = 0; rt < 2; ++rt) {
        const int row_l = w * 32 + rt * 16;
        floatx4 a1[8];
#pragma unroll
        for (int t = 0; t < 8; ++t) a1[t] = (floatx4){0.f, 0.f, 0.f, 0.f};
        bfrag bv = *(const bfrag*)(sea + (row_l + lr) * 40 + lg * 8);
#pragma unroll
        for (int t = 0; t < 8; ++t) {
            bfrag av = *(const bfrag*)(W1t + (t * 16 + lr) * 32 + lg * 8);
            a1[t] = MFMA(av, bv, a1[t]);
        }
        ushort* sHr = sH[w] + lr * 136;
#pragma unroll
        for (int t = 0; t < 8; ++t) {
            const float4 b1 = *(const float4*)(B1 + t * 16 + lg * 4);
            float h0 = gelu_t(a1[t][0] + b1.x), h1 = gelu_t(a1[t][1] + b1.y);
            float h2 = gelu_t(a1[t][2] + b1.z), h3 = gelu_t(a1[t][3] + b1.w);
            uint2 p;
            p.x = (unsigned)f2bf(h0) | ((unsigned)f2bf(h1) << 16);
            p.y = (unsigned)f2bf(h2) | ((unsigned)f2bf(h3) << 16);
            *(uint2*)(sHr + t * 16 + lg * 4) = p;
        }
        floatx4 a2[8];
#pragma unroll
        for (int t = 0; t < 8; ++t) a2[t] = (floatx4){0.f, 0.f, 0.f, 0.f};
#pragma unroll
        for (int kb = 0; kb < 4; ++kb) {
            bfrag av = *(const bfrag*)(sH[w] + lr * 136 + kb * 32 + lg * 8);
#pragma unroll
            for (int t = 0; t < 8; ++t) {
                bfrag bw = *(const bfrag*)(W2t + (t * 16 + lr) * 128 + kb * 32 + lg * 8);
                a2[t] = MFMA(av, bw, a2[t]);
            }
        }
        const int jlD = jl0 + row_l + lg * 4;
#pragma unroll
        for (int t = 0; t < 8; ++t) {
            const int col = t * 16 + lr;
            const float b2 = B2[col];
#pragma unroll
            for (int r = 0; r < 4; ++r) {
                int jl = jlD + r;
                if (S + jl < NE) ewp[(size_t)jl * 128 + col] = f2bf(a2[t][r] + b2);
            }
        }
    }
}

// ---------------- B: gather-multiply-segment-mean over sorted edges ----------------
__global__ void __launch_bounds__(256)
k_gms(const int* __restrict__ ei, const int* __restrict__ perm,
      const int* __restrict__ row_ptr, const int* __restrict__ nf,
      const int* __restrict__ nl, const ushort* __restrict__ ewp, int S,
      const ushort* __restrict__ mbf, ushort* __restrict__ aggbf) {
    __shared__ int ssrc[CAP], sdst[CAP], sseg[CAP];
    __shared__ int snode[64];
    __shared__ float sinvd[64];
    __shared__ float sagg[64 * 132];
    __shared__ int swtot[4];
    __shared__ int s_nseg;

    const int b = blockIdx.x;
    const int n0 = nf[b];
    if (n0 >= NN) return;
    const int n1 = nl[b];
    const int e0 = row_ptr[n0];
    int ne = row_ptr[n1 + 1] - e0;
    if (ne <= 0) return;
    const int ncl = (ne < CAP) ? ne : CAP;

    const int tid = threadIdx.x;
    const int w = tid >> 6, lane = tid & 63;

    for (int i = tid; i < 64 * 132; i += 256) sagg[i] = 0.0f;

    int dstv = -1 - tid;
    if (tid < ncl) {
        int e = perm[e0 + tid];
        ssrc[tid] = ei[e];
        dstv = ei[NE + e];
    }
    sdst[tid] = dstv;
    __syncthreads();

    int f = 0;
    if (tid < ncl) f = (tid == 0) ? 1 : (sdst[tid] != sdst[tid - 1]);
    unsigned long long mk = __ballot(f);
    int incl = __popcll(mk & (~0ull >> (63 - lane)));
    if (lane == 63) swtot[w] = incl;
    __syncthreads();
    int woff = 0;
    for (int i = 0; i < w; ++i) woff += swtot[i];
    int segid = woff + incl;
    sseg[tid] = segid - 1;
    if (f) {
        int s = segid - 1;
        snode[s] = dstv;
        sinvd[s] = 1.0f / (float)(row_ptr[dstv + 1] - row_ptr[dstv]);
    }
    if (tid == 255) s_nseg = segid;
    __syncthreads();
    const int nseg = s_nseg;

    const int c0 = (tid & 31) * 4;
    const int jb = (tid >> 5) * 32;
    const int be = e0 - S;
    int cs = -1;
    float v0 = 0.f, v1 = 0.f, v2 = 0.f, v3 = 0.f;
    for (int i = 0; i < 32; ++i) {
        int j = jb + i;
        if (j >= ncl) break;
        uint2 ew = *(const uint2*)(ewp + (size_t)(be + j) * 128 + c0);
        uint2 mv = *(const uint2*)(mbf + (size_t)ssrc[j] * 128 + c0);
        float a0 = bf2f((ushort)(ew.x & 0xFFFF)) * bf2f((ushort)(mv.x & 0xFFFF));
        float a1 = bf2f((ushort)(ew.x >> 16)) * bf2f((ushort)(mv.x >> 16));
        float a2 = bf2f((ushort)(ew.y & 0xFFFF)) * bf2f((ushort)(mv.y & 0xFFFF));
        float a3 = bf2f((ushort)(ew.y >> 16)) * bf2f((ushort)(mv.y >> 16));
        int sg = sseg[j];
        if (sg != cs) {
            if (cs >= 0) {
                float* p = &sagg[cs * 132 + c0];
                atomicAdd(p + 0, v0); atomicAdd(p + 1, v1);
                atomicAdd(p + 2, v2); atomicAdd(p + 3, v3);
            }
            cs = sg; v0 = a0; v1 = a1; v2 = a2; v3 = a3;
        } else {
            v0 += a0; v1 += a1; v2 += a2; v3 += a3;
        }
    }
    if (cs >= 0) {
        float* p = &sagg[cs * 132 + c0];
        atomicAdd(p + 0, v0); atomicAdd(p + 1, v1);
        atomicAdd(p + 2, v2); atomicAdd(p + 3, v3);
    }
    __syncthreads();
    for (int i = tid; i < nseg * 32; i += 256) {
        int s = i >> 5, qd = i & 31;
        float inv = sinvd[s];
        const float* p = &sagg[s * 132 + qd * 4];
        uint2 pk;
        pk.x = (unsigned)f2bf(p[0] * inv) | ((unsigned)f2bf(p[1] * inv) << 16);
        pk.y = (unsigned)f2bf(p[2] * inv) | ((unsigned)f2bf(p[3] * inv) << 16);
        *(uint2*)(aggbf + (size_t)snode[s] * 128 + qd * 4) = pk;
    }
}

// ---------------- gate + residual + LayerNorm (proven) ----------------
__global__ void __launch_bounds__(256)
k_gateln(ushort* __restrict__ hbf, const ushort* __restrict__ aggbf,
         float* __restrict__ hf,
         const ushort* __restrict__ GWt, const float* __restrict__ GB,
         const float* __restrict__ LNG, const float* __restrict__ LNB) {
    const int tid = threadIdx.x;
    const int w = tid >> 6, lane = tid & 63, lr = lane & 15, lg = lane >> 4;
    const int row = blockIdx.x * 64 + w * 16 + lr;

    floatx4 acc[8];
#pragma unroll
    for (int t = 0; t < 8; ++t) acc[t] = (floatx4){0.f, 0.f, 0.f, 0.f};
#pragma unroll
    for (int kb = 0; kb < 8; ++kb) {
        bfrag bv;
        if (kb < 4) bv = *(const bfrag*)(hbf + (size_t)row * 128 + kb * 32 + lg * 8);
        else bv = *(const bfrag*)(aggbf + (size_t)row * 128 + (kb - 4) * 32 + lg * 8);
#pragma unroll
        for (int t = 0; t < 8; ++t) {
            bfrag av = *(const bfrag*)(GWt + (t * 16 + lr) * 256 + kb * 32 + lg * 8);
            acc[t] = MFMA(av, bv, acc[t]);
        }
    }
    float o[8][4];
    float s = 0.0f;
#pragma unroll
    for (int t = 0; t < 8; ++t) {
        const int c0 = t * 16 + lg * 4;
        const float4 gb = *(const float4*)(GB + c0);
        const float4 hv = *(const float4*)(hf + (size_t)row * 128 + c0);
        uint2 ap = *(const uint2*)(aggbf + (size_t)row * 128 + c0);
        float a0 = bf2f((ushort)(ap.x & 0xFFFF)), a1 = bf2f((ushort)(ap.x >> 16));
        float a2 = bf2f((ushort)(ap.y & 0xFFFF)), a3 = bf2f((ushort)(ap.y >> 16));
        o[t][0] = hv.x + sigm(acc[t][0] + gb.x) * a0;
        o[t][1] = hv.y + sigm(acc[t][1] + gb.y) * a1;
        o[t][2] = hv.z + sigm(acc[t][2] + gb.z) * a2;
        o[t][3] = hv.w + sigm(acc[t][3] + gb.w) * a3;
        s += o[t][0] + o[t][1] + o[t][2] + o[t][3];
    }
    s += __shfl_xor(s, 16);
    s += __shfl_xor(s, 32);
    const float mu = s * (1.0f / 128.0f);
    float q = 0.0f;
#pragma unroll
    for (int t = 0; t < 8; ++t)
#pragma unroll
        for (int r = 0; r < 4; ++r) {
            float dx = o[t][r] - mu;
            q = fmaf(dx, dx, q);
        }
    q += __shfl_xor(q, 16);
    q += __shfl_xor(q, 32);
    const float rs = rsqrtf(q * (1.0f / 128.0f) + 1e-5f);

    if (row < NN) {
#pragma unroll
        for (int t = 0; t < 8; ++t) {
            const int c0 = t * 16 + lg * 4;
            const float4 g4 = *(const float4*)(LNG + c0);
            const float4 b4 = *(const float4*)(LNB + c0);
            float4 res;
            res.x = fmaf((o[t][0] - mu) * rs, g4.x, b4.x);
            res.y = fmaf((o[t][1] - mu) * rs, g4.y, b4.y);
            res.z = fmaf((o[t][2] - mu) * rs, g4.z, b4.z);
            res.w = fmaf((o[t][3] - mu) * rs, g4.w, b4.w);
            *(float4*)(hf + (size_t)row * 128 + c0) = res;
            uint2 pk;
            pk.x = (unsigned)f2bf(res.x) | ((unsigned)f2bf(res.y) << 16);
            pk.y = (unsigned)f2bf(res.z) | ((unsigned)f2bf(res.w) << 16);
            *(uint2*)(hbf + (size_t)row * 128 + c0) = pk;
        }
    }
}

// ---------------- heads (proven) ----------------
__global__ void __launch_bounds__(256)
k_headsmf(const ushort* __restrict__ hbf, float* __restrict__ OUT,
          const ushort* __restrict__ WHt,
          const float* __restrict__ b1a, const float* __restrict__ b1b, const float* __restrict__ b1c,
          const float* __restrict__ w2a, const float* __restrict__ w2b, const float* __restrict__ w2c,
          const float* __restrict__ b2a, const float* __restrict__ b2b, const float* __restrict__ b2c) {
    const int tid = threadIdx.x;
    const int w = tid >> 6, lane = tid & 63, lr = lane & 15, lg = lane >> 4;
    const int row = blockIdx.x * 64 + w * 16 + lr;

    floatx4 acc[12];
#pragma unroll
    for (int t = 0; t < 12; ++t) acc[t] = (floatx4){0.f, 0.f, 0.f, 0.f};
#pragma unroll
    for (int kb = 0; kb < 4; ++kb) {
        bfrag bv = *(const bfrag*)(hbf + (size_t)row * 128 + kb * 32 + lg * 8);
#pragma unroll
        for (int t = 0; t < 12; ++t) {
            bfrag av = *(const bfrag*)(WHt + (t * 16 + lr) * 128 + kb * 32 + lg * 8);
            acc[t] = MFMA(av, bv, acc[t]);
        }
    }
    const float* b1s[3] = {b1a, b1b, b1c};
    const float* w2s[3] = {w2a, w2b, w2c};
    float p[3] = {0.f, 0.f, 0.f};
#pragma unroll
    for (int t = 0; t < 12; ++t) {
        const int head = t >> 2;
        const int c0 = (t & 3) * 16 + lg * 4;
        const float4 b1 = *(const float4*)(b1s[head] + c0);
        const float4 w2 = *(const float4*)(w2s[head] + c0);
        p[head] += gelu_t(acc[t][0] + b1.x) * w2.x;
        p[head] += gelu_t(acc[t][1] + b1.y) * w2.y;
        p[head] += gelu_t(acc[t][2] + b1.z) * w2.z;
        p[head] += gelu_t(acc[t][3] + b1.w) * w2.w;
    }
#pragma unroll
    for (int hd = 0; hd < 3; ++hd) {
        p[hd] += __shfl_xor(p[hd], 16);
        p[hd] += __shfl_xor(p[hd], 32);
    }
    if (lg == 0 && row < NN) {
        OUT[0 * NN + row] = p[0] + b2a[0];
        OUT[1 * NN + row] = p[1] + b2b[0];
        OUT[2 * NN + row] = p[2] + b2c[0];
    }
}

extern "C" void kernel_launch(void* const* d_in, const int* in_sizes, int n_in,
                              void* d_out, int out_size, void* d_ws, size_t ws_size,
                              hipStream_t stream) {
    const float* x       = (const float*)d_in[0];
    const int*   ei      = (const int*)d_in[1];
    const float* ea      = (const float*)d_in[2];
    const float* enc_w1  = (const float*)d_in[3];
    const float* enc_b1  = (const float*)d_in[4];
    const float* enc_w2  = (const float*)d_in[5];
    const float* enc_b2  = (const float*)d_in[6];
    const float* edge_w1 = (const float*)d_in[7];
    const float* edge_b1 = (const float*)d_in[8];
    const float* edge_w2 = (const float*)d_in[9];
    const float* edge_b2 = (const float*)d_in[10];
    const float* msg_w1  = (const float*)d_in[11];
    const float* msg_b1  = (const float*)d_in[12];
    const float* msg_w2  = (const float*)d_in[13];
    const float* msg_b2  = (const float*)d_in[14];
    const float* gate_w  = (const float*)d_in[15];
    const float* gate_b  = (const float*)d_in[16];
    const float* ln_g    = (const float*)d_in[17];
    const float* ln_b    = (const float*)d_in[18];
    const float* hw[12];
    for (int t = 0; t < 12; ++t) hw[t] = (const float*)d_in[19 + t];

    const size_t NNH = (size_t)NN2 * H;
    float*  hf    = (float*)d_ws;
    ushort* hbf   = (ushort*)(hf + NNH);
    ushort* mbf   = hbf + NNH;
    ushort* aggbf = mbf + NNH;
    ushort* xbf   = aggbf + NNH;                   // NN2*32
    ushort* eapbf = xbf + (size_t)NN2 * 32;        // NE*16 (permuted)
    ushort* ewp   = eapbf + (size_t)NE * 16;       // PART_ROWS*128
    ushort* wt    = ewp + (size_t)PART_ROWS * 128;
    ushort* wt_enc1 = wt;                          // 128*32
    ushort* wt_enc2 = wt_enc1 + 128 * 32;          // 128*128
    ushort* wt_e1   = wt_enc2 + 128 * 128;         // 4*128*32
    ushort* wt_e2   = wt_e1 + 4 * 128 * 32;        // 4*128*128
    ushort* wt_m1   = wt_e2 + 4 * 128 * 128;       // 4*128*128
    ushort* wt_m2   = wt_m1 + 4 * 128 * 128;       // 4*128*128
    ushort* wt_g    = wt_m2 + 4 * 128 * 128;       // 4*128*256
    ushort* wt_h    = wt_g + 4 * 128 * 256;        // 192*128
    int* row_ptr = (int*)(wt_h + 192 * 128 + 64);
    int* perm    = row_ptr + 100352;
    int* nf      = perm + NE;
    int* nl      = nf + 10240;
    int* hist    = nl + 10240;
    int* incl    = hist + 100352;
    int* cursor  = incl + 100352;
    int* bsum    = cursor + 100352;

    // ---- sort by dst (CSR + perm) ----
    hipMemsetAsync(hist, 0, NN * sizeof(int), stream);
    hipMemsetAsync(nf, 0x7f, NB_E * sizeof(int), stream);
    hipMemsetAsync(nl, 0xff, NB_E * sizeof(int), stream);
    hipMemsetAsync(aggbf, 0, NNH * sizeof(ushort), stream);
    k_hist<<<(NE + 255) / 256, 256, 0, stream>>>(ei, hist);
    k_scan1<<<NSB, 256, 0, stream>>>(hist, incl, bsum);
    k_scan2<<<1, 512, 0, stream>>>(bsum);
    k_scan3<<<NSB, 256, 0, stream>>>(hist, incl, bsum, row_ptr);
    hipMemcpyAsync(cursor, row_ptr, NN * sizeof(int), hipMemcpyDeviceToDevice, stream);
    k_scatter<<<(NE + 255) / 256, 256, 0, stream>>>(ei, cursor, perm);
    k_blockrange<<<(NN + 255) / 256, 256, 0, stream>>>(row_ptr, nf, nl);

    // ---- converts ----
    k_wt<<<64, 256, 0, stream>>>(enc_w1, wt_enc1, 25, 128, 32, 128 * 32);
    k_wt<<<64, 256, 0, stream>>>(enc_w2, wt_enc2, 128, 128, 128, 128 * 128);
    k_wt<<<64, 256, 0, stream>>>(edge_w1, wt_e1, 10, 128, 32, 4 * 128 * 32);
    k_wt<<<256, 256, 0, stream>>>(edge_w2, wt_e2, 128, 128, 128, 4 * 128 * 128);
    k_wt<<<256, 256, 0, stream>>>(msg_w1, wt_m1, 128, 128, 128, 4 * 128 * 128);
    k_wt<<<256, 256, 0, stream>>>(msg_w2, wt_m2, 128, 128, 128, 4 * 128 * 128);
    k_wt<<<512, 256, 0, stream>>>(gate_w, wt_g, 256, 128, 256, 4 * 128 * 256);
    k_wt<<<32, 256, 0, stream>>>(hw[0], wt_h, 128, 64, 128, 64 * 128);
    k_wt<<<32, 256, 0, stream>>>(hw[4], wt_h + 64 * 128, 128, 64, 128, 64 * 128);
    k_wt<<<32, 256, 0, stream>>>(hw[8], wt_h + 128 * 128, 128, 64, 128, 64 * 128);
    k_cvt<<<3200, 256, 0, stream>>>(x, xbf, NN, 25, 32, NN2 * 32);
    k_cvtperm<<<(NE + 255) / 256, 256, 0, stream>>>(ea, perm, eapbf);

    // ---- network ----
    const int ntiles = NN2 / 64;
    k_mlp2mf<32, 1><<<ntiles, 256, 0, stream>>>(xbf, hbf, hf,
        wt_enc1, enc_b1, wt_enc2, enc_b2);

    for (int l = 0; l < NL; ++l) {
        k_mlp2mf<128, 0><<<ntiles, 256, 0, stream>>>(hbf, mbf, nullptr,
            wt_m1 + (size_t)l * 128 * 128, msg_b1 + l * H,
            wt_m2 + (size_t)l * 128 * 128, msg_b2 + l * H);
        for (int p = 0; p < 4; ++p) {
            const int S = p * PART_E;
            k_ew<<<PART_BLK, 256, 0, stream>>>(eapbf, ewp, S,
                wt_e1 + (size_t)l * 128 * 32, edge_b1 + l * H,
                wt_e2 + (size_t)l * 128 * 128, edge_b2 + l * H);
            const int nb = (p == 3) ? (PART_GB + 1) : PART_GB;
            k_gms<<<nb, 256, 0, stream>>>(ei, perm, row_ptr,
                nf + p * PART_GB, nl + p * PART_GB, ewp, S, mbf, aggbf);
        }
        k_gateln<<<ntiles, 256, 0, stream>>>(hbf, aggbf, hf,
            wt_g + (size_t)l * 128 * 256, gate_b + l * H,
            ln_g + l * H, ln_b + l * H);
    }

    k_headsmf<<<ntiles, 256, 0, stream>>>(hbf, (float*)d_out, wt_h,
        hw[1], hw[5], hw[9], hw[2], hw[6], hw[10], hw[3], hw[7], hw[11]);
}

// Round 5
// 2408.541 us; speedup vs baseline: 2.5729x; 1.1507x over previous
//
#include <hip/hip_runtime.h>
#include <math.h>

#define NN 100000
#define NN2 100032               // padded to 64 rows
#define NE 640000
#define H 128
#define AD 25
#define ED 10
#define RD 64
#define NL 4
#define NB_E (NE / 64 + 1)       // 10001 edge blocks
#define NSB ((NN + 255) / 256)   // 391 scan blocks
#define CAP 256

typedef short bfrag __attribute__((ext_vector_type(8)));
typedef float floatx4 __attribute__((ext_vector_type(4)));
typedef unsigned short ushort;

#define MFMA(a, b, c) __builtin_amdgcn_mfma_f32_16x16x32_bf16(a, b, c, 0, 0, 0)

__device__ __forceinline__ ushort f2bf(float f) {
    unsigned u = __float_as_uint(f);
    unsigned r = (u + 0x7FFFu + ((u >> 16) & 1u)) >> 16;
    return (ushort)r;
}
__device__ __forceinline__ float bf2f(ushort b) {
    return __uint_as_float(((unsigned)b) << 16);
}
__device__ __forceinline__ float gelu_t(float x) {
    float u = 0.7978845608028654f * (x + 0.044715f * x * x * x);
    float e = __expf(2.0f * u);
    float th = 1.0f - 2.0f / (e + 1.0f);
    return 0.5f * x * (1.0f + th);
}
__device__ __forceinline__ float sigm(float x) {
    return 1.0f / (1.0f + __expf(-x));
}

// ---------------- weight transpose+convert ----------------
__global__ void k_wt(const float* __restrict__ src, ushort* __restrict__ dst,
                     int Ks, int N, int Kd, int total) {
    for (int idx = blockIdx.x * 256 + threadIdx.x; idx < total; idx += gridDim.x * 256) {
        int nk = N * Kd;
        int b = idx / nk;
        int rem = idx - b * nk;
        int n = rem / Kd, k = rem - n * Kd;
        float v = (k < Ks) ? src[((size_t)b * Ks + k) * N + n] : 0.0f;
        dst[idx] = f2bf(v);
    }
}
__global__ void k_cvt(const float* __restrict__ src, ushort* __restrict__ dst,
                      int rs, int Ks, int Kd, int total) {
    for (int idx = blockIdx.x * 256 + threadIdx.x; idx < total; idx += gridDim.x * 256) {
        int r = idx / Kd, k = idx - r * Kd;
        dst[idx] = (r < rs && k < Ks) ? f2bf(src[(size_t)r * Ks + k]) : 0;
    }
}
__global__ void k_cvtperm(const float* __restrict__ ea, const int* __restrict__ perm,
                          ushort* __restrict__ out) {
    int j = blockIdx.x * 256 + threadIdx.x;
    if (j >= NE) return;
    const float* src = ea + (size_t)perm[j] * ED;
    unsigned u[8];
#pragma unroll
    for (int k = 0; k < 5; ++k)
        u[k] = (unsigned)f2bf(src[2 * k]) | ((unsigned)f2bf(src[2 * k + 1]) << 16);
    u[5] = u[6] = u[7] = 0u;
    uint4* o = (uint4*)(out + (size_t)j * 16);
    uint4 a; a.x = u[0]; a.y = u[1]; a.z = u[2]; a.w = u[3];
    uint4 b; b.x = u[4]; b.y = u[5]; b.z = u[6]; b.w = u[7];
    o[0] = a; o[1] = b;
}

// ---------------- sort infrastructure (proven) ----------------
__global__ void k_hist(const int* __restrict__ ei, int* __restrict__ hist) {
    int e = blockIdx.x * 256 + threadIdx.x;
    if (e < NE) atomicAdd(&hist[ei[NE + e]], 1);
}
__global__ void k_scan1(const int* __restrict__ hist, int* __restrict__ incl,
                        int* __restrict__ bsum) {
    __shared__ int s[256];
    int tid = threadIdx.x;
    int i = blockIdx.x * 256 + tid;
    s[tid] = (i < NN) ? hist[i] : 0;
    __syncthreads();
    for (int off = 1; off < 256; off <<= 1) {
        int t = (tid >= off) ? s[tid - off] : 0;
        __syncthreads();
        s[tid] += t;
        __syncthreads();
    }
    if (i < NN) incl[i] = s[tid];
    if (tid == 255) bsum[blockIdx.x] = s[255];
}
__global__ void k_scan2(int* __restrict__ bsum) {
    __shared__ int s[512];
    int tid = threadIdx.x;
    s[tid] = (tid < NSB) ? bsum[tid] : 0;
    __syncthreads();
    for (int off = 1; off < 512; off <<= 1) {
        int t = (tid >= off) ? s[tid - off] : 0;
        __syncthreads();
        s[tid] += t;
        __syncthreads();
    }
    if (tid < NSB) bsum[tid] = (tid > 0) ? s[tid - 1] : 0;
}
__global__ void k_scan3(const int* __restrict__ hist, const int* __restrict__ incl,
                        const int* __restrict__ bsum, int* __restrict__ row_ptr) {
    int i = blockIdx.x * 256 + threadIdx.x;
    if (i < NN) row_ptr[i] = bsum[blockIdx.x] + incl[i] - hist[i];
    if (i == 0) row_ptr[NN] = NE;
}
__global__ void k_scatter(const int* __restrict__ ei, int* __restrict__ cursor,
                          int* __restrict__ perm) {
    int e = blockIdx.x * 256 + threadIdx.x;
    if (e < NE) {
        int d = ei[NE + e];
        int pos = atomicAdd(&cursor[d], 1);
        perm[pos] = e;
    }
}
__global__ void k_blockrange(const int* __restrict__ row_ptr, int* __restrict__ nf,
                             int* __restrict__ nl) {
    int n = blockIdx.x * 256 + threadIdx.x;
    if (n < NN) {
        int b = row_ptr[n] >> 6;
        atomicMin(&nf[b], n);
        atomicMax(&nl[b], n);
    }
}

// ---------------- MFMA node MLP2 (proven) ----------------
template <int K1, int WH>
__global__ void __launch_bounds__(256)
k_mlp2mf(const ushort* __restrict__ Abf, ushort* __restrict__ Obf, float* __restrict__ Of32,
         const ushort* __restrict__ W1t, const float* __restrict__ B1,
         const ushort* __restrict__ W2t, const float* __restrict__ B2) {
    __shared__ ushort sH[64 * 136];
    const int tid = threadIdx.x;
    const int w = tid >> 6, lane = tid & 63, lr = lane & 15, lg = lane >> 4;
    const int rowB = blockIdx.x * 64 + w * 16 + lr;

    floatx4 acc[8];
#pragma unroll
    for (int t = 0; t < 8; ++t) acc[t] = (floatx4){0.f, 0.f, 0.f, 0.f};
#pragma unroll
    for (int kb = 0; kb < K1 / 32; ++kb) {
        bfrag bv = *(const bfrag*)(Abf + (size_t)rowB * K1 + kb * 32 + lg * 8);
#pragma unroll
        for (int t = 0; t < 8; ++t) {
            bfrag av = *(const bfrag*)(W1t + (t * 16 + lr) * K1 + kb * 32 + lg * 8);
            acc[t] = MFMA(av, bv, acc[t]);
        }
    }
    ushort* sHrow = sH + (w * 16 + lr) * 136;
#pragma unroll
    for (int t = 0; t < 8; ++t) {
        const float4 b1 = *(const float4*)(B1 + t * 16 + lg * 4);
        float h0 = gelu_t(acc[t][0] + b1.x), h1 = gelu_t(acc[t][1] + b1.y);
        float h2 = gelu_t(acc[t][2] + b1.z), h3 = gelu_t(acc[t][3] + b1.w);
        uint2 p;
        p.x = (unsigned)f2bf(h0) | ((unsigned)f2bf(h1) << 16);
        p.y = (unsigned)f2bf(h2) | ((unsigned)f2bf(h3) << 16);
        *(uint2*)(sHrow + t * 16 + lg * 4) = p;
    }
#pragma unroll
    for (int t = 0; t < 8; ++t) acc[t] = (floatx4){0.f, 0.f, 0.f, 0.f};
#pragma unroll
    for (int kb = 0; kb < 4; ++kb) {
        bfrag av = *(const bfrag*)(sH + (w * 16 + lr) * 136 + kb * 32 + lg * 8);
#pragma unroll
        for (int t = 0; t < 8; ++t) {
            bfrag bv = *(const bfrag*)(W2t + (t * 16 + lr) * 128 + kb * 32 + lg * 8);
            acc[t] = MFMA(av, bv, acc[t]);
        }
    }
    const int rowD = blockIdx.x * 64 + w * 16 + lg * 4;
#pragma unroll
    for (int t = 0; t < 8; ++t) {
        const int col = t * 16 + lr;
        const float b2 = B2[col];
#pragma unroll
        for (int r = 0; r < 4; ++r) {
            int row = rowD + r;
            if (row < NN) {
                float v = acc[t][r] + b2;
                Obf[(size_t)row * 128 + col] = f2bf(v);
                if (WH) Of32[(size_t)row * 128 + col] = v;
            }
        }
    }
}

// ---------------- A: edge-weight GEMM over sorted edges ----------------
__global__ void __launch_bounds__(256)
k_ew(const ushort* __restrict__ eap, ushort* __restrict__ ewp, int S,
     const ushort* __restrict__ W1t, const float* __restrict__ B1,
     const ushort* __restrict__ W2t, const float* __restrict__ B2) {
    __shared__ ushort sea[128 * 40];
    __shared__ ushort sH[4][16 * 136];
    const int tid = threadIdx.x;
    const int w = tid >> 6, lane = tid & 63, lr = lane & 15, lg = lane >> 4;
    const int jl0 = blockIdx.x * 128;

    {
        int r = tid >> 1, half = tid & 1;
        int j = S + jl0 + r;
        uint4 z; z.x = z.y = z.z = z.w = 0u;
        uint4 v = z;
        if (j < NE) v = *(const uint4*)(eap + (size_t)j * 16 + half * 8);
        *(uint4*)(sea + r * 40 + half * 8) = v;
        *(uint4*)(sea + r * 40 + 16 + half * 8) = z;
    }
    __syncthreads();

    for (int rt = 0; rt < 2; ++rt) {
        const int row_l = w * 32 + rt * 16;
        floatx4 a1[8];
#pragma unroll
        for (int t = 0; t < 8; ++t) a1[t] = (floatx4){0.f, 0.f, 0.f, 0.f};
        bfrag bv = *(const bfrag*)(sea + (row_l + lr) * 40 + lg * 8);
#pragma unroll
        for (int t = 0; t < 8; ++t) {
            bfrag av = *(const bfrag*)(W1t + (t * 16 + lr) * 32 + lg * 8);
            a1[t] = MFMA(av, bv, a1[t]);
        }
        ushort* sHr = sH[w] + lr * 136;
#pragma unroll
        for (int t = 0; t < 8; ++t) {
            const float4 b1 = *(const float4*)(B1 + t * 16 + lg * 4);
            float h0 = gelu_t(a1[t][0] + b1.x), h1 = gelu_t(a1[t][1] + b1.y);
            float h2 = gelu_t(a1[t][2] + b1.z), h3 = gelu_t(a1[t][3] + b1.w);
            uint2 p;
            p.x = (unsigned)f2bf(h0) | ((unsigned)f2bf(h1) << 16);
            p.y = (unsigned)f2bf(h2) | ((unsigned)f2bf(h3) << 16);
            *(uint2*)(sHr + t * 16 + lg * 4) = p;
        }
        floatx4 a2[8];
#pragma unroll
        for (int t = 0; t < 8; ++t) a2[t] = (floatx4){0.f, 0.f, 0.f, 0.f};
#pragma unroll
        for (int kb = 0; kb < 4; ++kb) {
            bfrag av = *(const bfrag*)(sH[w] + lr * 136 + kb * 32 + lg * 8);
#pragma unroll
            for (int t = 0; t < 8; ++t) {
                bfrag bw = *(const bfrag*)(W2t + (t * 16 + lr) * 128 + kb * 32 + lg * 8);
                a2[t] = MFMA(av, bw, a2[t]);
            }
        }
        const int jlD = jl0 + row_l + lg * 4;
#pragma unroll
        for (int t = 0; t < 8; ++t) {
            const int col = t * 16 + lr;
            const float b2 = B2[col];
#pragma unroll
            for (int r = 0; r < 4; ++r) {
                int jl = jlD + r;
                if (S + jl < NE) ewp[(size_t)jl * 128 + col] = f2bf(a2[t][r] + b2);
            }
        }
    }
}

// ---------------- B: gather-multiply-segment-mean (balanced) ----------------
__global__ void __launch_bounds__(256)
k_gms(const int* __restrict__ ei, const int* __restrict__ perm,
      const int* __restrict__ row_ptr, const int* __restrict__ nf,
      const int* __restrict__ nl, const ushort* __restrict__ ewp, int S,
      const ushort* __restrict__ mbf, ushort* __restrict__ aggbf) {
    __shared__ int ssrc[CAP], sdst[CAP], sseg[CAP];
    __shared__ int snode[64];
    __shared__ float sinvd[64];
    __shared__ float sagg[64 * 132];
    __shared__ int swtot[4];
    __shared__ int s_nseg;

    const int b = blockIdx.x;
    const int n0 = nf[b];
    if (n0 >= NN) return;
    const int n1 = nl[b];
    const int e0 = row_ptr[n0];
    int ne = row_ptr[n1 + 1] - e0;
    if (ne <= 0) return;
    const int ncl = (ne < CAP) ? ne : CAP;

    const int tid = threadIdx.x;
    const int w = tid >> 6, lane = tid & 63;

    for (int i = tid; i < 64 * 132; i += 256) sagg[i] = 0.0f;

    int dstv = -1 - tid;
    if (tid < ncl) {
        int e = perm[e0 + tid];
        ssrc[tid] = ei[e];
        dstv = ei[NE + e];
    }
    sdst[tid] = dstv;
    __syncthreads();

    int f = 0;
    if (tid < ncl) f = (tid == 0) ? 1 : (sdst[tid] != sdst[tid - 1]);
    unsigned long long mk = __ballot(f);
    int incl = __popcll(mk & (~0ull >> (63 - lane)));
    if (lane == 63) swtot[w] = incl;
    __syncthreads();
    int woff = 0;
    for (int i = 0; i < w; ++i) woff += swtot[i];
    int segid = woff + incl;
    sseg[tid] = segid - 1;
    if (f) {
        int s = segid - 1;
        snode[s] = dstv;
        sinvd[s] = 1.0f / (float)(row_ptr[dstv + 1] - row_ptr[dstv]);
    }
    if (tid == 255) s_nseg = segid;
    __syncthreads();
    const int nseg = s_nseg;

    // balanced: 8 thread-groups (32 lanes = 128 cols) split ncl evenly
    const int c0 = (tid & 31) * 4;
    const int g = tid >> 5;
    const int chunk = (ncl + 7) >> 3;
    const int j0 = g * chunk;
    const int j1 = (j0 + chunk < ncl) ? (j0 + chunk) : ncl;
    const int be = e0 - S;
    int cs = -1;
    float v0 = 0.f, v1 = 0.f, v2 = 0.f, v3 = 0.f;
    for (int j = j0; j < j1; ++j) {
        uint2 ew = *(const uint2*)(ewp + (size_t)(be + j) * 128 + c0);
        uint2 mv = *(const uint2*)(mbf + (size_t)ssrc[j] * 128 + c0);
        float a0 = bf2f((ushort)(ew.x & 0xFFFF)) * bf2f((ushort)(mv.x & 0xFFFF));
        float a1 = bf2f((ushort)(ew.x >> 16)) * bf2f((ushort)(mv.x >> 16));
        float a2 = bf2f((ushort)(ew.y & 0xFFFF)) * bf2f((ushort)(mv.y & 0xFFFF));
        float a3 = bf2f((ushort)(ew.y >> 16)) * bf2f((ushort)(mv.y >> 16));
        int sg = sseg[j];
        if (sg != cs) {
            if (cs >= 0) {
                float* p = &sagg[cs * 132 + c0];
                atomicAdd(p + 0, v0); atomicAdd(p + 1, v1);
                atomicAdd(p + 2, v2); atomicAdd(p + 3, v3);
            }
            cs = sg; v0 = a0; v1 = a1; v2 = a2; v3 = a3;
        } else {
            v0 += a0; v1 += a1; v2 += a2; v3 += a3;
        }
    }
    if (cs >= 0) {
        float* p = &sagg[cs * 132 + c0];
        atomicAdd(p + 0, v0); atomicAdd(p + 1, v1);
        atomicAdd(p + 2, v2); atomicAdd(p + 3, v3);
    }
    __syncthreads();
    for (int i = tid; i < nseg * 32; i += 256) {
        int s = i >> 5, qd = i & 31;
        float inv = sinvd[s];
        const float* p = &sagg[s * 132 + qd * 4];
        uint2 pk;
        pk.x = (unsigned)f2bf(p[0] * inv) | ((unsigned)f2bf(p[1] * inv) << 16);
        pk.y = (unsigned)f2bf(p[2] * inv) | ((unsigned)f2bf(p[3] * inv) << 16);
        *(uint2*)(aggbf + (size_t)snode[s] * 128 + qd * 4) = pk;
    }
}

// ---------------- gate + residual + LayerNorm (proven) ----------------
__global__ void __launch_bounds__(256)
k_gateln(ushort* __restrict__ hbf, const ushort* __restrict__ aggbf,
         float* __restrict__ hf,
         const ushort* __restrict__ GWt, const float* __restrict__ GB,
         const float* __restrict__ LNG, const float* __restrict__ LNB) {
    const int tid = threadIdx.x;
    const int w = tid >> 6, lane = tid & 63, lr = lane & 15, lg = lane >> 4;
    const int row = blockIdx.x * 64 + w * 16 + lr;

    floatx4 acc[8];
#pragma unroll
    for (int t = 0; t < 8; ++t) acc[t] = (floatx4){0.f, 0.f, 0.f, 0.f};
#pragma unroll
    for (int kb = 0; kb < 8; ++kb) {
        bfrag bv;
        if (kb < 4) bv = *(const bfrag*)(hbf + (size_t)row * 128 + kb * 32 + lg * 8);
        else bv = *(const bfrag*)(aggbf + (size_t)row * 128 + (kb - 4) * 32 + lg * 8);
#pragma unroll
        for (int t = 0; t < 8; ++t) {
            bfrag av = *(const bfrag*)(GWt + (t * 16 + lr) * 256 + kb * 32 + lg * 8);
            acc[t] = MFMA(av, bv, acc[t]);
        }
    }
    float o[8][4];
    float s = 0.0f;
#pragma unroll
    for (int t = 0; t < 8; ++t) {
        const int c0 = t * 16 + lg * 4;
        const float4 gb = *(const float4*)(GB + c0);
        const float4 hv = *(const float4*)(hf + (size_t)row * 128 + c0);
        uint2 ap = *(const uint2*)(aggbf + (size_t)row * 128 + c0);
        float a0 = bf2f((ushort)(ap.x & 0xFFFF)), a1 = bf2f((ushort)(ap.x >> 16));
        float a2 = bf2f((ushort)(ap.y & 0xFFFF)), a3 = bf2f((ushort)(ap.y >> 16));
        o[t][0] = hv.x + sigm(acc[t][0] + gb.x) * a0;
        o[t][1] = hv.y + sigm(acc[t][1] + gb.y) * a1;
        o[t][2] = hv.z + sigm(acc[t][2] + gb.z) * a2;
        o[t][3] = hv.w + sigm(acc[t][3] + gb.w) * a3;
        s += o[t][0] + o[t][1] + o[t][2] + o[t][3];
    }
    s += __shfl_xor(s, 16);
    s += __shfl_xor(s, 32);
    const float mu = s * (1.0f / 128.0f);
    float q = 0.0f;
#pragma unroll
    for (int t = 0; t < 8; ++t)
#pragma unroll
        for (int r = 0; r < 4; ++r) {
            float dx = o[t][r] - mu;
            q = fmaf(dx, dx, q);
        }
    q += __shfl_xor(q, 16);
    q += __shfl_xor(q, 32);
    const float rs = rsqrtf(q * (1.0f / 128.0f) + 1e-5f);

    if (row < NN) {
#pragma unroll
        for (int t = 0; t < 8; ++t) {
            const int c0 = t * 16 + lg * 4;
            const float4 g4 = *(const float4*)(LNG + c0);
            const float4 b4 = *(const float4*)(LNB + c0);
            float4 res;
            res.x = fmaf((o[t][0] - mu) * rs, g4.x, b4.x);
            res.y = fmaf((o[t][1] - mu) * rs, g4.y, b4.y);
            res.z = fmaf((o[t][2] - mu) * rs, g4.z, b4.z);
            res.w = fmaf((o[t][3] - mu) * rs, g4.w, b4.w);
            *(float4*)(hf + (size_t)row * 128 + c0) = res;
            uint2 pk;
            pk.x = (unsigned)f2bf(res.x) | ((unsigned)f2bf(res.y) << 16);
            pk.y = (unsigned)f2bf(res.z) | ((unsigned)f2bf(res.w) << 16);
            *(uint2*)(hbf + (size_t)row * 128 + c0) = pk;
        }
    }
}

// ---------------- heads (proven) ----------------
__global__ void __launch_bounds__(256)
k_headsmf(const ushort* __restrict__ hbf, float* __restrict__ OUT,
          const ushort* __restrict__ WHt,
          const float* __restrict__ b1a, const float* __restrict__ b1b, const float* __restrict__ b1c,
          const float* __restrict__ w2a, const float* __restrict__ w2b, const float* __restrict__ w2c,
          const float* __restrict__ b2a, const float* __restrict__ b2b, const float* __restrict__ b2c) {
    const int tid = threadIdx.x;
    const int w = tid >> 6, lane = tid & 63, lr = lane & 15, lg = lane >> 4;
    const int row = blockIdx.x * 64 + w * 16 + lr;

    floatx4 acc[12];
#pragma unroll
    for (int t = 0; t < 12; ++t) acc[t] = (floatx4){0.f, 0.f, 0.f, 0.f};
#pragma unroll
    for (int kb = 0; kb < 4; ++kb) {
        bfrag bv = *(const bfrag*)(hbf + (size_t)row * 128 + kb * 32 + lg * 8);
#pragma unroll
        for (int t = 0; t < 12; ++t) {
            bfrag av = *(const bfrag*)(WHt + (t * 16 + lr) * 128 + kb * 32 + lg * 8);
            acc[t] = MFMA(av, bv, acc[t]);
        }
    }
    const float* b1s[3] = {b1a, b1b, b1c};
    const float* w2s[3] = {w2a, w2b, w2c};
    float p[3] = {0.f, 0.f, 0.f};
#pragma unroll
    for (int t = 0; t < 12; ++t) {
        const int head = t >> 2;
        const int c0 = (t & 3) * 16 + lg * 4;
        const float4 b1 = *(const float4*)(b1s[head] + c0);
        const float4 w2 = *(const float4*)(w2s[head] + c0);
        p[head] += gelu_t(acc[t][0] + b1.x) * w2.x;
        p[head] += gelu_t(acc[t][1] + b1.y) * w2.y;
        p[head] += gelu_t(acc[t][2] + b1.z) * w2.z;
        p[head] += gelu_t(acc[t][3] + b1.w) * w2.w;
    }
#pragma unroll
    for (int hd = 0; hd < 3; ++hd) {
        p[hd] += __shfl_xor(p[hd], 16);
        p[hd] += __shfl_xor(p[hd], 32);
    }
    if (lg == 0 && row < NN) {
        OUT[0 * NN + row] = p[0] + b2a[0];
        OUT[1 * NN + row] = p[1] + b2b[0];
        OUT[2 * NN + row] = p[2] + b2c[0];
    }
}

extern "C" void kernel_launch(void* const* d_in, const int* in_sizes, int n_in,
                              void* d_out, int out_size, void* d_ws, size_t ws_size,
                              hipStream_t stream) {
    const float* x       = (const float*)d_in[0];
    const int*   ei      = (const int*)d_in[1];
    const float* ea      = (const float*)d_in[2];
    const float* enc_w1  = (const float*)d_in[3];
    const float* enc_b1  = (const float*)d_in[4];
    const float* enc_w2  = (const float*)d_in[5];
    const float* enc_b2  = (const float*)d_in[6];
    const float* edge_w1 = (const float*)d_in[7];
    const float* edge_b1 = (const float*)d_in[8];
    const float* edge_w2 = (const float*)d_in[9];
    const float* edge_b2 = (const float*)d_in[10];
    const float* msg_w1  = (const float*)d_in[11];
    const float* msg_b1  = (const float*)d_in[12];
    const float* msg_w2  = (const float*)d_in[13];
    const float* msg_b2  = (const float*)d_in[14];
    const float* gate_w  = (const float*)d_in[15];
    const float* gate_b  = (const float*)d_in[16];
    const float* ln_g    = (const float*)d_in[17];
    const float* ln_b    = (const float*)d_in[18];
    const float* hw[12];
    for (int t = 0; t < 12; ++t) hw[t] = (const float*)d_in[19 + t];

    const size_t NNH = (size_t)NN2 * H;
    float*  hf    = (float*)d_ws;
    ushort* hbf   = (ushort*)(hf + NNH);
    ushort* mbf   = hbf + NNH;
    ushort* aggbf = mbf + NNH;
    ushort* xbf   = aggbf + NNH;                   // NN2*32
    ushort* eapbf = xbf + (size_t)NN2 * 32;        // NE*16 (permuted)
    ushort* wt    = eapbf + (size_t)NE * 16;
    ushort* wt_enc1 = wt;                          // 128*32
    ushort* wt_enc2 = wt_enc1 + 128 * 32;          // 128*128
    ushort* wt_e1   = wt_enc2 + 128 * 128;         // 4*128*32
    ushort* wt_e2   = wt_e1 + 4 * 128 * 32;        // 4*128*128
    ushort* wt_m1   = wt_e2 + 4 * 128 * 128;       // 4*128*128
    ushort* wt_m2   = wt_m1 + 4 * 128 * 128;       // 4*128*128
    ushort* wt_g    = wt_m2 + 4 * 128 * 128;       // 4*128*256
    ushort* wt_h    = wt_g + 4 * 128 * 256;        // 192*128
    int* row_ptr = (int*)(wt_h + 192 * 128 + 64);
    int* perm    = row_ptr + 100352;
    int* nf      = perm + NE;
    int* nl      = nf + 10240;
    int* hist    = nl + 10240;
    int* incl    = hist + 100352;
    int* cursor  = incl + 100352;
    int* bsum    = cursor + 100352;
    // ewp goes last; align to 16B
    uintptr_t ewp_addr = ((uintptr_t)(bsum + 512) + 15) & ~(uintptr_t)15;
    ushort* ewp = (ushort*)ewp_addr;
    const size_t used = ewp_addr - (uintptr_t)d_ws;

    // pick partition count: largest ewp that fits
    int P = 4;
    size_t rows = NE / 4 + 1024;
    if (ws_size >= used + (size_t)NE * 128 * 2) { P = 1; rows = NE; }
    else if (ws_size >= used + ((size_t)NE / 2 + 1024) * 128 * 2) { P = 2; rows = NE / 2 + 1024; }
    const int PE = NE / P;           // edges per part
    const int NGB = 10000 / P;       // 64-edge groups per part
    const int ewblk = (int)(rows / 128);

    // ---- sort by dst (CSR + perm) ----
    hipMemsetAsync(hist, 0, NN * sizeof(int), stream);
    hipMemsetAsync(nf, 0x7f, NB_E * sizeof(int), stream);
    hipMemsetAsync(nl, 0xff, NB_E * sizeof(int), stream);
    hipMemsetAsync(aggbf, 0, NNH * sizeof(ushort), stream);
    k_hist<<<(NE + 255) / 256, 256, 0, stream>>>(ei, hist);
    k_scan1<<<NSB, 256, 0, stream>>>(hist, incl, bsum);
    k_scan2<<<1, 512, 0, stream>>>(bsum);
    k_scan3<<<NSB, 256, 0, stream>>>(hist, incl, bsum, row_ptr);
    hipMemcpyAsync(cursor, row_ptr, NN * sizeof(int), hipMemcpyDeviceToDevice, stream);
    k_scatter<<<(NE + 255) / 256, 256, 0, stream>>>(ei, cursor, perm);
    k_blockrange<<<(NN + 255) / 256, 256, 0, stream>>>(row_ptr, nf, nl);

    // ---- converts ----
    k_wt<<<64, 256, 0, stream>>>(enc_w1, wt_enc1, 25, 128, 32, 128 * 32);
    k_wt<<<64, 256, 0, stream>>>(enc_w2, wt_enc2, 128, 128, 128, 128 * 128);
    k_wt<<<64, 256, 0, stream>>>(edge_w1, wt_e1, 10, 128, 32, 4 * 128 * 32);
    k_wt<<<256, 256, 0, stream>>>(edge_w2, wt_e2, 128, 128, 128, 4 * 128 * 128);
    k_wt<<<256, 256, 0, stream>>>(msg_w1, wt_m1, 128, 128, 128, 4 * 128 * 128);
    k_wt<<<256, 256, 0, stream>>>(msg_w2, wt_m2, 128, 128, 128, 4 * 128 * 128);
    k_wt<<<512, 256, 0, stream>>>(gate_w, wt_g, 256, 128, 256, 4 * 128 * 256);
    k_wt<<<32, 256, 0, stream>>>(hw[0], wt_h, 128, 64, 128, 64 * 128);
    k_wt<<<32, 256, 0, stream>>>(hw[4], wt_h + 64 * 128, 128, 64, 128, 64 * 128);
    k_wt<<<32, 256, 0, stream>>>(hw[8], wt_h + 128 * 128, 128, 64, 128, 64 * 128);
    k_cvt<<<3200, 256, 0, stream>>>(x, xbf, NN, 25, 32, NN2 * 32);
    k_cvtperm<<<(NE + 255) / 256, 256, 0, stream>>>(ea, perm, eapbf);

    // ---- network ----
    const int ntiles = NN2 / 64;
    k_mlp2mf<32, 1><<<ntiles, 256, 0, stream>>>(xbf, hbf, hf,
        wt_enc1, enc_b1, wt_enc2, enc_b2);

    for (int l = 0; l < NL; ++l) {
        k_mlp2mf<128, 0><<<ntiles, 256, 0, stream>>>(hbf, mbf, nullptr,
            wt_m1 + (size_t)l * 128 * 128, msg_b1 + l * H,
            wt_m2 + (size_t)l * 128 * 128, msg_b2 + l * H);
        for (int p = 0; p < P; ++p) {
            const int S = p * PE;
            k_ew<<<ewblk, 256, 0, stream>>>(eapbf, ewp, S,
                wt_e1 + (size_t)l * 128 * 32, edge_b1 + l * H,
                wt_e2 + (size_t)l * 128 * 128, edge_b2 + l * H);
            const int nb = (p == P - 1) ? (NGB + 1) : NGB;
            k_gms<<<nb, 256, 0, stream>>>(ei, perm, row_ptr,
                nf + p * NGB, nl + p * NGB, ewp, S, mbf, aggbf);
        }
        k_gateln<<<ntiles, 256, 0, stream>>>(hbf, aggbf, hf,
            wt_g + (size_t)l * 128 * 256, gate_b + l * H,
            ln_g + l * H, ln_b + l * H);
    }

    k_headsmf<<<ntiles, 256, 0, stream>>>(hbf, (float*)d_out, wt_h,
        hw[1], hw[5], hw[9], hw[2], hw[6], hw[10], hw[3], hw[7], hw[11]);
}

// Round 6
// 2286.802 us; speedup vs baseline: 2.7099x; 1.0532x over previous
//
#include <hip/hip_runtime.h>
#include <math.h>

#define NN 100000
#define NN2 100032               // padded to 64 rows
#define NE 640000
#define H 128
#define AD 25
#define ED 10
#define RD 64
#define NL 4
#define NB_E (NE / 64 + 1)       // 10001 edge blocks
#define NSB ((NN + 255) / 256)   // 391 scan blocks
#define CAP 256

typedef short bfrag __attribute__((ext_vector_type(8)));
typedef float floatx4 __attribute__((ext_vector_type(4)));
typedef unsigned short ushort;

#define MFMA(a, b, c) __builtin_amdgcn_mfma_f32_16x16x32_bf16(a, b, c, 0, 0, 0)

__device__ __forceinline__ ushort f2bf(float f) {
    unsigned u = __float_as_uint(f);
    unsigned r = (u + 0x7FFFu + ((u >> 16) & 1u)) >> 16;
    return (ushort)r;
}
__device__ __forceinline__ float bf2f(ushort b) {
    return __uint_as_float(((unsigned)b) << 16);
}
__device__ __forceinline__ float gelu_t(float x) {
    float u = 0.7978845608028654f * (x + 0.044715f * x * x * x);
    float e = __expf(2.0f * u);
    float th = 1.0f - 2.0f / (e + 1.0f);
    return 0.5f * x * (1.0f + th);
}
__device__ __forceinline__ float sigm(float x) {
    return 1.0f / (1.0f + __expf(-x));
}

// ---------------- weight transpose+convert ----------------
__global__ void k_wt(const float* __restrict__ src, ushort* __restrict__ dst,
                     int Ks, int N, int Kd, int total) {
    for (int idx = blockIdx.x * 256 + threadIdx.x; idx < total; idx += gridDim.x * 256) {
        int nk = N * Kd;
        int b = idx / nk;
        int rem = idx - b * nk;
        int n = rem / Kd, k = rem - n * Kd;
        float v = (k < Ks) ? src[((size_t)b * Ks + k) * N + n] : 0.0f;
        dst[idx] = f2bf(v);
    }
}
__global__ void k_cvt(const float* __restrict__ src, ushort* __restrict__ dst,
                      int rs, int Ks, int Kd, int total) {
    for (int idx = blockIdx.x * 256 + threadIdx.x; idx < total; idx += gridDim.x * 256) {
        int r = idx / Kd, k = idx - r * Kd;
        dst[idx] = (r < rs && k < Ks) ? f2bf(src[(size_t)r * Ks + k]) : 0;
    }
}
__global__ void k_cvtperm(const float* __restrict__ ea, const int* __restrict__ perm,
                          ushort* __restrict__ out) {
    int j = blockIdx.x * 256 + threadIdx.x;
    if (j >= NE) return;
    const float* src = ea + (size_t)perm[j] * ED;
    unsigned u[8];
#pragma unroll
    for (int k = 0; k < 5; ++k)
        u[k] = (unsigned)f2bf(src[2 * k]) | ((unsigned)f2bf(src[2 * k + 1]) << 16);
    u[5] = u[6] = u[7] = 0u;
    uint4* o = (uint4*)(out + (size_t)j * 16);
    uint4 a; a.x = u[0]; a.y = u[1]; a.z = u[2]; a.w = u[3];
    uint4 b; b.x = u[4]; b.y = u[5]; b.z = u[6]; b.w = u[7];
    o[0] = a; o[1] = b;
}

// ---------------- sort infrastructure (proven) ----------------
__global__ void k_hist(const int* __restrict__ ei, int* __restrict__ hist) {
    int e = blockIdx.x * 256 + threadIdx.x;
    if (e < NE) atomicAdd(&hist[ei[NE + e]], 1);
}
__global__ void k_scan1(const int* __restrict__ hist, int* __restrict__ incl,
                        int* __restrict__ bsum) {
    __shared__ int s[256];
    int tid = threadIdx.x;
    int i = blockIdx.x * 256 + tid;
    s[tid] = (i < NN) ? hist[i] : 0;
    __syncthreads();
    for (int off = 1; off < 256; off <<= 1) {
        int t = (tid >= off) ? s[tid - off] : 0;
        __syncthreads();
        s[tid] += t;
        __syncthreads();
    }
    if (i < NN) incl[i] = s[tid];
    if (tid == 255) bsum[blockIdx.x] = s[255];
}
__global__ void k_scan2(int* __restrict__ bsum) {
    __shared__ int s[512];
    int tid = threadIdx.x;
    s[tid] = (tid < NSB) ? bsum[tid] : 0;
    __syncthreads();
    for (int off = 1; off < 512; off <<= 1) {
        int t = (tid >= off) ? s[tid - off] : 0;
        __syncthreads();
        s[tid] += t;
        __syncthreads();
    }
    if (tid < NSB) bsum[tid] = (tid > 0) ? s[tid - 1] : 0;
}
__global__ void k_scan3(const int* __restrict__ hist, const int* __restrict__ incl,
                        const int* __restrict__ bsum, int* __restrict__ row_ptr) {
    int i = blockIdx.x * 256 + threadIdx.x;
    if (i < NN) row_ptr[i] = bsum[blockIdx.x] + incl[i] - hist[i];
    if (i == 0) row_ptr[NN] = NE;
}
__global__ void k_scatter(const int* __restrict__ ei, int* __restrict__ cursor,
                          int* __restrict__ perm) {
    int e = blockIdx.x * 256 + threadIdx.x;
    if (e < NE) {
        int d = ei[NE + e];
        int pos = atomicAdd(&cursor[d], 1);
        perm[pos] = e;
    }
}
__global__ void k_blockrange(const int* __restrict__ row_ptr, int* __restrict__ nf,
                             int* __restrict__ nl) {
    int n = blockIdx.x * 256 + threadIdx.x;
    if (n < NN) {
        int b = row_ptr[n] >> 6;
        atomicMin(&nf[b], n);
        atomicMax(&nl[b], n);
    }
}

// ---------------- MFMA node MLP2 (proven; f32 output removed) ----------------
template <int K1>
__global__ void __launch_bounds__(256)
k_mlp2mf(const ushort* __restrict__ Abf, ushort* __restrict__ Obf,
         const ushort* __restrict__ W1t, const float* __restrict__ B1,
         const ushort* __restrict__ W2t, const float* __restrict__ B2) {
    __shared__ ushort sH[64 * 136];
    const int tid = threadIdx.x;
    const int w = tid >> 6, lane = tid & 63, lr = lane & 15, lg = lane >> 4;
    const int rowB = blockIdx.x * 64 + w * 16 + lr;

    floatx4 acc[8];
#pragma unroll
    for (int t = 0; t < 8; ++t) acc[t] = (floatx4){0.f, 0.f, 0.f, 0.f};
#pragma unroll
    for (int kb = 0; kb < K1 / 32; ++kb) {
        bfrag bv = *(const bfrag*)(Abf + (size_t)rowB * K1 + kb * 32 + lg * 8);
#pragma unroll
        for (int t = 0; t < 8; ++t) {
            bfrag av = *(const bfrag*)(W1t + (t * 16 + lr) * K1 + kb * 32 + lg * 8);
            acc[t] = MFMA(av, bv, acc[t]);
        }
    }
    ushort* sHrow = sH + (w * 16 + lr) * 136;
#pragma unroll
    for (int t = 0; t < 8; ++t) {
        const float4 b1 = *(const float4*)(B1 + t * 16 + lg * 4);
        float h0 = gelu_t(acc[t][0] + b1.x), h1 = gelu_t(acc[t][1] + b1.y);
        float h2 = gelu_t(acc[t][2] + b1.z), h3 = gelu_t(acc[t][3] + b1.w);
        uint2 p;
        p.x = (unsigned)f2bf(h0) | ((unsigned)f2bf(h1) << 16);
        p.y = (unsigned)f2bf(h2) | ((unsigned)f2bf(h3) << 16);
        *(uint2*)(sHrow + t * 16 + lg * 4) = p;
    }
#pragma unroll
    for (int t = 0; t < 8; ++t) acc[t] = (floatx4){0.f, 0.f, 0.f, 0.f};
#pragma unroll
    for (int kb = 0; kb < 4; ++kb) {
        bfrag av = *(const bfrag*)(sH + (w * 16 + lr) * 136 + kb * 32 + lg * 8);
#pragma unroll
        for (int t = 0; t < 8; ++t) {
            bfrag bv = *(const bfrag*)(W2t + (t * 16 + lr) * 128 + kb * 32 + lg * 8);
            acc[t] = MFMA(av, bv, acc[t]);
        }
    }
    const int rowD = blockIdx.x * 64 + w * 16 + lg * 4;
#pragma unroll
    for (int t = 0; t < 8; ++t) {
        const int col = t * 16 + lr;
        const float b2 = B2[col];
#pragma unroll
        for (int r = 0; r < 4; ++r) {
            int row = rowD + r;
            if (row < NN) Obf[(size_t)row * 128 + col] = f2bf(acc[t][r] + b2);
        }
    }
}

// ---------------- A: edge-weight GEMM, swapped G2 -> coalesced uint2 stores ----
__global__ void __launch_bounds__(256)
k_ew(const ushort* __restrict__ eap, ushort* __restrict__ ewp, int S,
     const ushort* __restrict__ W1t, const float* __restrict__ B1,
     const ushort* __restrict__ W2t, const float* __restrict__ B2) {
    __shared__ ushort sea[128 * 40];
    __shared__ ushort sH[4][16 * 136];
    const int tid = threadIdx.x;
    const int w = tid >> 6, lane = tid & 63, lr = lane & 15, lg = lane >> 4;
    const int jl0 = blockIdx.x * 128;

    {
        int r = tid >> 1, half = tid & 1;
        int j = S + jl0 + r;
        uint4 z; z.x = z.y = z.z = z.w = 0u;
        uint4 v = z;
        if (j < NE) v = *(const uint4*)(eap + (size_t)j * 16 + half * 8);
        *(uint4*)(sea + r * 40 + half * 8) = v;
        *(uint4*)(sea + r * 40 + 16 + half * 8) = z;
    }
    __syncthreads();

    for (int rt = 0; rt < 2; ++rt) {
        const int row_l = w * 32 + rt * 16;
        floatx4 a1[8];
#pragma unroll
        for (int t = 0; t < 8; ++t) a1[t] = (floatx4){0.f, 0.f, 0.f, 0.f};
        bfrag bv = *(const bfrag*)(sea + (row_l + lr) * 40 + lg * 8);
#pragma unroll
        for (int t = 0; t < 8; ++t) {
            bfrag av = *(const bfrag*)(W1t + (t * 16 + lr) * 32 + lg * 8);
            a1[t] = MFMA(av, bv, a1[t]);
        }
        ushort* sHr = sH[w] + lr * 136;
#pragma unroll
        for (int t = 0; t < 8; ++t) {
            const float4 b1 = *(const float4*)(B1 + t * 16 + lg * 4);
            float h0 = gelu_t(a1[t][0] + b1.x), h1 = gelu_t(a1[t][1] + b1.y);
            float h2 = gelu_t(a1[t][2] + b1.z), h3 = gelu_t(a1[t][3] + b1.w);
            uint2 p;
            p.x = (unsigned)f2bf(h0) | ((unsigned)f2bf(h1) << 16);
            p.y = (unsigned)f2bf(h2) | ((unsigned)f2bf(h3) << 16);
            *(uint2*)(sHr + t * 16 + lg * 4) = p;
        }
        // G2 SWAPPED: MFMA(W2t_frag, hidden_frag)
        //  -> D[(lg*4+r) = channel within t-tile][(lane&15) = edge]
        //  lane holds edge (row_l+lr), channels t*16+lg*4+{0..3}
        floatx4 a2[8];
#pragma unroll
        for (int t = 0; t < 8; ++t) a2[t] = (floatx4){0.f, 0.f, 0.f, 0.f};
#pragma unroll
        for (int kb = 0; kb < 4; ++kb) {
            bfrag av = *(const bfrag*)(sH[w] + lr * 136 + kb * 32 + lg * 8);
#pragma unroll
            for (int t = 0; t < 8; ++t) {
                bfrag bw = *(const bfrag*)(W2t + (t * 16 + lr) * 128 + kb * 32 + lg * 8);
                a2[t] = MFMA(bw, av, a2[t]);
            }
        }
        const int jl = jl0 + row_l + lr;
        if (S + jl < NE) {
            ushort* orow = ewp + (size_t)jl * 128;
#pragma unroll
            for (int t = 0; t < 8; ++t) {
                const float4 b2 = *(const float4*)(B2 + t * 16 + lg * 4);
                uint2 p;
                p.x = (unsigned)f2bf(a2[t][0] + b2.x) |
                      ((unsigned)f2bf(a2[t][1] + b2.y) << 16);
                p.y = (unsigned)f2bf(a2[t][2] + b2.z) |
                      ((unsigned)f2bf(a2[t][3] + b2.w) << 16);
                *(uint2*)(orow + t * 16 + lg * 4) = p;
            }
        }
    }
}

// ---------------- B: gather-multiply-segment-mean (balanced, proven) ----------
__global__ void __launch_bounds__(256)
k_gms(const int* __restrict__ ei, const int* __restrict__ perm,
      const int* __restrict__ row_ptr, const int* __restrict__ nf,
      const int* __restrict__ nl, const ushort* __restrict__ ewp, int S,
      const ushort* __restrict__ mbf, ushort* __restrict__ aggbf) {
    __shared__ int ssrc[CAP], sdst[CAP], sseg[CAP];
    __shared__ int snode[64];
    __shared__ float sinvd[64];
    __shared__ float sagg[64 * 132];
    __shared__ int swtot[4];
    __shared__ int s_nseg;

    const int b = blockIdx.x;
    const int n0 = nf[b];
    if (n0 >= NN) return;
    const int n1 = nl[b];
    const int e0 = row_ptr[n0];
    int ne = row_ptr[n1 + 1] - e0;
    if (ne <= 0) return;
    const int ncl = (ne < CAP) ? ne : CAP;

    const int tid = threadIdx.x;
    const int w = tid >> 6, lane = tid & 63;

    for (int i = tid; i < 64 * 132; i += 256) sagg[i] = 0.0f;

    int dstv = -1 - tid;
    if (tid < ncl) {
        int e = perm[e0 + tid];
        ssrc[tid] = ei[e];
        dstv = ei[NE + e];
    }
    sdst[tid] = dstv;
    __syncthreads();

    int f = 0;
    if (tid < ncl) f = (tid == 0) ? 1 : (sdst[tid] != sdst[tid - 1]);
    unsigned long long mk = __ballot(f);
    int incl = __popcll(mk & (~0ull >> (63 - lane)));
    if (lane == 63) swtot[w] = incl;
    __syncthreads();
    int woff = 0;
    for (int i = 0; i < w; ++i) woff += swtot[i];
    int segid = woff + incl;
    sseg[tid] = segid - 1;
    if (f) {
        int s = segid - 1;
        snode[s] = dstv;
        sinvd[s] = 1.0f / (float)(row_ptr[dstv + 1] - row_ptr[dstv]);
    }
    if (tid == 255) s_nseg = segid;
    __syncthreads();
    const int nseg = s_nseg;

    const int c0 = (tid & 31) * 4;
    const int g = tid >> 5;
    const int chunk = (ncl + 7) >> 3;
    const int j0 = g * chunk;
    const int j1 = (j0 + chunk < ncl) ? (j0 + chunk) : ncl;
    const int be = e0 - S;
    int cs = -1;
    float v0 = 0.f, v1 = 0.f, v2 = 0.f, v3 = 0.f;
    for (int j = j0; j < j1; ++j) {
        uint2 ew = *(const uint2*)(ewp + (size_t)(be + j) * 128 + c0);
        uint2 mv = *(const uint2*)(mbf + (size_t)ssrc[j] * 128 + c0);
        float a0 = bf2f((ushort)(ew.x & 0xFFFF)) * bf2f((ushort)(mv.x & 0xFFFF));
        float a1 = bf2f((ushort)(ew.x >> 16)) * bf2f((ushort)(mv.x >> 16));
        float a2 = bf2f((ushort)(ew.y & 0xFFFF)) * bf2f((ushort)(mv.y & 0xFFFF));
        float a3 = bf2f((ushort)(ew.y >> 16)) * bf2f((ushort)(mv.y >> 16));
        int sg = sseg[j];
        if (sg != cs) {
            if (cs >= 0) {
                float* p = &sagg[cs * 132 + c0];
                atomicAdd(p + 0, v0); atomicAdd(p + 1, v1);
                atomicAdd(p + 2, v2); atomicAdd(p + 3, v3);
            }
            cs = sg; v0 = a0; v1 = a1; v2 = a2; v3 = a3;
        } else {
            v0 += a0; v1 += a1; v2 += a2; v3 += a3;
        }
    }
    if (cs >= 0) {
        float* p = &sagg[cs * 132 + c0];
        atomicAdd(p + 0, v0); atomicAdd(p + 1, v1);
        atomicAdd(p + 2, v2); atomicAdd(p + 3, v3);
    }
    __syncthreads();
    for (int i = tid; i < nseg * 32; i += 256) {
        int s = i >> 5, qd = i & 31;
        float inv = sinvd[s];
        const float* p = &sagg[s * 132 + qd * 4];
        uint2 pk;
        pk.x = (unsigned)f2bf(p[0] * inv) | ((unsigned)f2bf(p[1] * inv) << 16);
        pk.y = (unsigned)f2bf(p[2] * inv) | ((unsigned)f2bf(p[3] * inv) << 16);
        *(uint2*)(aggbf + (size_t)snode[s] * 128 + qd * 4) = pk;
    }
}

// ---------------- gate + residual + LayerNorm (bf16 trunk) ----------------
__global__ void __launch_bounds__(256)
k_gateln(ushort* __restrict__ hbf, const ushort* __restrict__ aggbf,
         const ushort* __restrict__ GWt, const float* __restrict__ GB,
         const float* __restrict__ LNG, const float* __restrict__ LNB) {
    const int tid = threadIdx.x;
    const int w = tid >> 6, lane = tid & 63, lr = lane & 15, lg = lane >> 4;
    const int row = blockIdx.x * 64 + w * 16 + lr;

    floatx4 acc[8];
#pragma unroll
    for (int t = 0; t < 8; ++t) acc[t] = (floatx4){0.f, 0.f, 0.f, 0.f};
#pragma unroll
    for (int kb = 0; kb < 8; ++kb) {
        bfrag bv;
        if (kb < 4) bv = *(const bfrag*)(hbf + (size_t)row * 128 + kb * 32 + lg * 8);
        else bv = *(const bfrag*)(aggbf + (size_t)row * 128 + (kb - 4) * 32 + lg * 8);
#pragma unroll
        for (int t = 0; t < 8; ++t) {
            bfrag av = *(const bfrag*)(GWt + (t * 16 + lr) * 256 + kb * 32 + lg * 8);
            acc[t] = MFMA(av, bv, acc[t]);
        }
    }
    float o[8][4];
    float s = 0.0f;
#pragma unroll
    for (int t = 0; t < 8; ++t) {
        const int c0 = t * 16 + lg * 4;
        const float4 gb = *(const float4*)(GB + c0);
        uint2 hp = *(const uint2*)(hbf + (size_t)row * 128 + c0);
        uint2 ap = *(const uint2*)(aggbf + (size_t)row * 128 + c0);
        float h0 = bf2f((ushort)(hp.x & 0xFFFF)), h1 = bf2f((ushort)(hp.x >> 16));
        float h2 = bf2f((ushort)(hp.y & 0xFFFF)), h3 = bf2f((ushort)(hp.y >> 16));
        float a0 = bf2f((ushort)(ap.x & 0xFFFF)), a1 = bf2f((ushort)(ap.x >> 16));
        float a2 = bf2f((ushort)(ap.y & 0xFFFF)), a3 = bf2f((ushort)(ap.y >> 16));
        o[t][0] = h0 + sigm(acc[t][0] + gb.x) * a0;
        o[t][1] = h1 + sigm(acc[t][1] + gb.y) * a1;
        o[t][2] = h2 + sigm(acc[t][2] + gb.z) * a2;
        o[t][3] = h3 + sigm(acc[t][3] + gb.w) * a3;
        s += o[t][0] + o[t][1] + o[t][2] + o[t][3];
    }
    s += __shfl_xor(s, 16);
    s += __shfl_xor(s, 32);
    const float mu = s * (1.0f / 128.0f);
    float q = 0.0f;
#pragma unroll
    for (int t = 0; t < 8; ++t)
#pragma unroll
        for (int r = 0; r < 4; ++r) {
            float dx = o[t][r] - mu;
            q = fmaf(dx, dx, q);
        }
    q += __shfl_xor(q, 16);
    q += __shfl_xor(q, 32);
    const float rs = rsqrtf(q * (1.0f / 128.0f) + 1e-5f);

    if (row < NN) {
#pragma unroll
        for (int t = 0; t < 8; ++t) {
            const int c0 = t * 16 + lg * 4;
            const float4 g4 = *(const float4*)(LNG + c0);
            const float4 b4 = *(const float4*)(LNB + c0);
            float r0 = fmaf((o[t][0] - mu) * rs, g4.x, b4.x);
            float r1 = fmaf((o[t][1] - mu) * rs, g4.y, b4.y);
            float r2 = fmaf((o[t][2] - mu) * rs, g4.z, b4.z);
            float r3 = fmaf((o[t][3] - mu) * rs, g4.w, b4.w);
            uint2 pk;
            pk.x = (unsigned)f2bf(r0) | ((unsigned)f2bf(r1) << 16);
            pk.y = (unsigned)f2bf(r2) | ((unsigned)f2bf(r3) << 16);
            *(uint2*)(hbf + (size_t)row * 128 + c0) = pk;
        }
    }
}

// ---------------- heads (proven) ----------------
__global__ void __launch_bounds__(256)
k_headsmf(const ushort* __restrict__ hbf, float* __restrict__ OUT,
          const ushort* __restrict__ WHt,
          const float* __restrict__ b1a, const float* __restrict__ b1b, const float* __restrict__ b1c,
          const float* __restrict__ w2a, const float* __restrict__ w2b, const float* __restrict__ w2c,
          const float* __restrict__ b2a, const float* __restrict__ b2b, const float* __restrict__ b2c) {
    const int tid = threadIdx.x;
    const int w = tid >> 6, lane = tid & 63, lr = lane & 15, lg = lane >> 4;
    const int row = blockIdx.x * 64 + w * 16 + lr;

    floatx4 acc[12];
#pragma unroll
    for (int t = 0; t < 12; ++t) acc[t] = (floatx4){0.f, 0.f, 0.f, 0.f};
#pragma unroll
    for (int kb = 0; kb < 4; ++kb) {
        bfrag bv = *(const bfrag*)(hbf + (size_t)row * 128 + kb * 32 + lg * 8);
#pragma unroll
        for (int t = 0; t < 12; ++t) {
            bfrag av = *(const bfrag*)(WHt + (t * 16 + lr) * 128 + kb * 32 + lg * 8);
            acc[t] = MFMA(av, bv, acc[t]);
        }
    }
    const float* b1s[3] = {b1a, b1b, b1c};
    const float* w2s[3] = {w2a, w2b, w2c};
    float p[3] = {0.f, 0.f, 0.f};
#pragma unroll
    for (int t = 0; t < 12; ++t) {
        const int head = t >> 2;
        const int c0 = (t & 3) * 16 + lg * 4;
        const float4 b1 = *(const float4*)(b1s[head] + c0);
        const float4 w2 = *(const float4*)(w2s[head] + c0);
        p[head] += gelu_t(acc[t][0] + b1.x) * w2.x;
        p[head] += gelu_t(acc[t][1] + b1.y) * w2.y;
        p[head] += gelu_t(acc[t][2] + b1.z) * w2.z;
        p[head] += gelu_t(acc[t][3] + b1.w) * w2.w;
    }
#pragma unroll
    for (int hd = 0; hd < 3; ++hd) {
        p[hd] += __shfl_xor(p[hd], 16);
        p[hd] += __shfl_xor(p[hd], 32);
    }
    if (lg == 0 && row < NN) {
        OUT[0 * NN + row] = p[0] + b2a[0];
        OUT[1 * NN + row] = p[1] + b2b[0];
        OUT[2 * NN + row] = p[2] + b2c[0];
    }
}

extern "C" void kernel_launch(void* const* d_in, const int* in_sizes, int n_in,
                              void* d_out, int out_size, void* d_ws, size_t ws_size,
                              hipStream_t stream) {
    const float* x       = (const float*)d_in[0];
    const int*   ei      = (const int*)d_in[1];
    const float* ea      = (const float*)d_in[2];
    const float* enc_w1  = (const float*)d_in[3];
    const float* enc_b1  = (const float*)d_in[4];
    const float* enc_w2  = (const float*)d_in[5];
    const float* enc_b2  = (const float*)d_in[6];
    const float* edge_w1 = (const float*)d_in[7];
    const float* edge_b1 = (const float*)d_in[8];
    const float* edge_w2 = (const float*)d_in[9];
    const float* edge_b2 = (const float*)d_in[10];
    const float* msg_w1  = (const float*)d_in[11];
    const float* msg_b1  = (const float*)d_in[12];
    const float* msg_w2  = (const float*)d_in[13];
    const float* msg_b2  = (const float*)d_in[14];
    const float* gate_w  = (const float*)d_in[15];
    const float* gate_b  = (const float*)d_in[16];
    const float* ln_g    = (const float*)d_in[17];
    const float* ln_b    = (const float*)d_in[18];
    const float* hw[12];
    for (int t = 0; t < 12; ++t) hw[t] = (const float*)d_in[19 + t];

    const size_t NNH = (size_t)NN2 * H;
    ushort* hbf   = (ushort*)d_ws;
    ushort* mbf   = hbf + NNH;
    ushort* aggbf = mbf + NNH;
    ushort* xbf   = aggbf + NNH;                   // NN2*32
    ushort* eapbf = xbf + (size_t)NN2 * 32;        // NE*16 (permuted)
    ushort* wt    = eapbf + (size_t)NE * 16;
    ushort* wt_enc1 = wt;                          // 128*32
    ushort* wt_enc2 = wt_enc1 + 128 * 32;          // 128*128
    ushort* wt_e1   = wt_enc2 + 128 * 128;         // 4*128*32
    ushort* wt_e2   = wt_e1 + 4 * 128 * 32;        // 4*128*128
    ushort* wt_m1   = wt_e2 + 4 * 128 * 128;       // 4*128*128
    ushort* wt_m2   = wt_m1 + 4 * 128 * 128;       // 4*128*128
    ushort* wt_g    = wt_m2 + 4 * 128 * 128;       // 4*128*256
    ushort* wt_h    = wt_g + 4 * 128 * 256;        // 192*128
    int* row_ptr = (int*)(wt_h + 192 * 128 + 64);
    int* perm    = row_ptr + 100352;
    int* nf      = perm + NE;
    int* nl      = nf + 10240;
    int* hist    = nl + 10240;
    int* incl    = hist + 100352;
    int* cursor  = incl + 100352;
    int* bsum    = cursor + 100352;
    uintptr_t ewp_addr = ((uintptr_t)(bsum + 512) + 15) & ~(uintptr_t)15;
    ushort* ewp = (ushort*)ewp_addr;
    const size_t used = ewp_addr - (uintptr_t)d_ws;

    int P = 4;
    size_t rows = NE / 4 + 1024;
    if (ws_size >= used + (size_t)NE * 128 * 2) { P = 1; rows = NE; }
    else if (ws_size >= used + ((size_t)NE / 2 + 1024) * 128 * 2) { P = 2; rows = NE / 2 + 1024; }
    const int PE = NE / P;
    const int NGB = 10000 / P;
    const int ewblk = (int)(rows / 128);

    // ---- sort by dst (CSR + perm) ----
    hipMemsetAsync(hist, 0, NN * sizeof(int), stream);
    hipMemsetAsync(nf, 0x7f, NB_E * sizeof(int), stream);
    hipMemsetAsync(nl, 0xff, NB_E * sizeof(int), stream);
    hipMemsetAsync(aggbf, 0, NNH * sizeof(ushort), stream);
    k_hist<<<(NE + 255) / 256, 256, 0, stream>>>(ei, hist);
    k_scan1<<<NSB, 256, 0, stream>>>(hist, incl, bsum);
    k_scan2<<<1, 512, 0, stream>>>(bsum);
    k_scan3<<<NSB, 256, 0, stream>>>(hist, incl, bsum, row_ptr);
    hipMemcpyAsync(cursor, row_ptr, NN * sizeof(int), hipMemcpyDeviceToDevice, stream);
    k_scatter<<<(NE + 255) / 256, 256, 0, stream>>>(ei, cursor, perm);
    k_blockrange<<<(NN + 255) / 256, 256, 0, stream>>>(row_ptr, nf, nl);

    // ---- converts ----
    k_wt<<<64, 256, 0, stream>>>(enc_w1, wt_enc1, 25, 128, 32, 128 * 32);
    k_wt<<<64, 256, 0, stream>>>(enc_w2, wt_enc2, 128, 128, 128, 128 * 128);
    k_wt<<<64, 256, 0, stream>>>(edge_w1, wt_e1, 10, 128, 32, 4 * 128 * 32);
    k_wt<<<256, 256, 0, stream>>>(edge_w2, wt_e2, 128, 128, 128, 4 * 128 * 128);
    k_wt<<<256, 256, 0, stream>>>(msg_w1, wt_m1, 128, 128, 128, 4 * 128 * 128);
    k_wt<<<256, 256, 0, stream>>>(msg_w2, wt_m2, 128, 128, 128, 4 * 128 * 128);
    k_wt<<<512, 256, 0, stream>>>(gate_w, wt_g, 256, 128, 256, 4 * 128 * 256);
    k_wt<<<32, 256, 0, stream>>>(hw[0], wt_h, 128, 64, 128, 64 * 128);
    k_wt<<<32, 256, 0, stream>>>(hw[4], wt_h + 64 * 128, 128, 64, 128, 64 * 128);
    k_wt<<<32, 256, 0, stream>>>(hw[8], wt_h + 128 * 128, 128, 64, 128, 64 * 128);
    k_cvt<<<3200, 256, 0, stream>>>(x, xbf, NN, 25, 32, NN2 * 32);
    k_cvtperm<<<(NE + 255) / 256, 256, 0, stream>>>(ea, perm, eapbf);

    // ---- network ----
    const int ntiles = NN2 / 64;
    k_mlp2mf<32><<<ntiles, 256, 0, stream>>>(xbf, hbf,
        wt_enc1, enc_b1, wt_enc2, enc_b2);

    for (int l = 0; l < NL; ++l) {
        k_mlp2mf<128><<<ntiles, 256, 0, stream>>>(hbf, mbf,
            wt_m1 + (size_t)l * 128 * 128, msg_b1 + l * H,
            wt_m2 + (size_t)l * 128 * 128, msg_b2 + l * H);
        for (int p = 0; p < P; ++p) {
            const int S = p * PE;
            k_ew<<<ewblk, 256, 0, stream>>>(eapbf, ewp, S,
                wt_e1 + (size_t)l * 128 * 32, edge_b1 + l * H,
                wt_e2 + (size_t)l * 128 * 128, edge_b2 + l * H);
            const int nb = (p == P - 1) ? (NGB + 1) : NGB;
            k_gms<<<nb, 256, 0, stream>>>(ei, perm, row_ptr,
                nf + p * NGB, nl + p * NGB, ewp, S, mbf, aggbf);
        }
        k_gateln<<<ntiles, 256, 0, stream>>>(hbf, aggbf,
            wt_g + (size_t)l * 128 * 256, gate_b + l * H,
            ln_g + l * H, ln_b + l * H);
    }

    k_headsmf<<<ntiles, 256, 0, stream>>>(hbf, (float*)d_out, wt_h,
        hw[1], hw[5], hw[9], hw[2], hw[6], hw[10], hw[3], hw[7], hw[11]);
}